// Round 12
// baseline (418.127 us; speedup 1.0000x reference)
//
#include <hip/hip_runtime.h>
#include <math.h>

typedef __attribute__((ext_vector_type(8))) short bf16x8;
typedef __attribute__((ext_vector_type(4))) float f32x4;
typedef unsigned int uint32;
typedef unsigned short ushort;

namespace {
constexpr int KK = 24, BB = 128;

constexpr size_t SZ_W1P = (size_t)24 * 128 * 32 * 2;
constexpr size_t SZ_W5P = (size_t)24 * 32 * 128 * 2;
constexpr size_t SZ_WB  = (size_t)24 * 128 * 1152 * 2;
constexpr size_t OFF_W1P = 0;
constexpr size_t OFF_W5P = OFF_W1P + SZ_W1P;
constexpr size_t OFF_WB2 = OFF_W5P + SZ_W5P;
constexpr size_t OFF_WB3 = OFF_WB2 + SZ_WB;
constexpr size_t OFF_WB4 = OFF_WB3 + SZ_WB;
constexpr size_t OFF_TT  = OFF_WB4 + SZ_WB;      // bf16 tt
constexpr size_t SZ_TT   = (size_t)128 * 24 * 1600 * 2;
constexpr size_t OFF_SMAX = OFF_TT + SZ_TT;
constexpr size_t OFF_SDEN = OFF_SMAX + 12288;
constexpr size_t OFF_DM   = OFF_SDEN + 12288;
constexpr size_t OFF_PART = OFF_DM + 12288;

constexpr long long O_OCAE = 1;
constexpr long long O_XM   = O_OCAE + (long long)BB * KK * 144;
constexpr long long O_DM   = O_XM + (long long)BB * KK * 6;

// ---- phase-aliased LDS (byte offsets into R1); 2 images per block ----
constexpr int R1_SZ   = 80864;
constexpr int XIM_OFF = 0;       // ush [2][361][16] = 23,104
constexpr int H1T_OFF = 23104;   // ush [2][361][40] = 57,760 -> 80,864
constexpr int XSB_OFF = 74464;   // ush [2][1600] (tail of h1T img1; dead before conv1)
constexpr int H2S_OFF = 0;       // ush [2][4][81][40] = 51,840
constexpr int H3S_OFF = 0;       // ush [2][4][49][40] = 31,360
constexpr int H4B_OFF = 31392;   // ush [2][25][136] = 13,600 -> 44,992
constexpr int OUTS_OFF = 0;      // f32 [2][600] = 4,800
constexpr int ATT_OFF = 4800;    // f32 [2][25]
constexpr int PS_OFF  = 5000;    // f32 [2][23] -> 5,184
}

__device__ inline ushort f2bf(float f) {
  uint32 u = __builtin_bit_cast(uint32, f);
  u += 0x7fffu + ((u >> 16) & 1u);
  return (ushort)(u >> 16);
}
__device__ inline float bf2f(ushort u) {
  return __builtin_bit_cast(float, (uint32)u << 16);
}
__device__ inline uint32 cvtpk(float a, float b) {
  uint32 r;
  asm("v_cvt_pk_bf16_f32 %0, %1, %2" : "=v"(r) : "v"(a), "v"(b));
  return r;
}
// LDS-only barrier: drains LDS ops but leaves global loads in flight (no vmcnt(0)).
__device__ inline void bar_lds() {
  asm volatile("s_waitcnt lgkmcnt(0)\n\ts_barrier" ::: "memory");
}

// ---------------- weight permutes ----------------
// W1p[k][co][32] with k=9 slot = b1 (bias folded via xim k9=1.0); W5p[k][fm(32,pad0)][128]
__global__ __launch_bounds__(128) void k_w1p(const float* __restrict__ W1,
                                             const float* __restrict__ W5,
                                             const float* __restrict__ b1,
                                             ushort* __restrict__ W1p,
                                             ushort* __restrict__ W5p) {
  const int k = blockIdx.x, t = threadIdx.x;
  {
    ushort tmp[32];
    #pragma unroll
    for (int i = 0; i < 32; ++i) tmp[i] = 0;
    #pragma unroll
    for (int j = 0; j < 9; ++j) tmp[j] = f2bf(W1[(k * 128 + t) * 9 + j]);
    tmp[9] = f2bf(b1[k * 128 + t]);
    uint4* dp = (uint4*)(W1p + ((size_t)k * 128 + t) * 32);
    #pragma unroll
    for (int i = 0; i < 4; ++i) dp[i] = ((uint4*)tmp)[i];
  }
  if (t < 32) {
    ushort* dp = W5p + ((size_t)k * 32 + t) * 128;
    if (t < 24) {
      const float* sp = W5 + (size_t)k * 3072 + t * 128;
      for (int ci = 0; ci < 128; ++ci) dp[ci] = f2bf(sp[ci]);
    } else {
      for (int ci = 0; ci < 128; ++ci) dp[ci] = 0;
    }
  }
}

__global__ __launch_bounds__(256) void k_wp(
    const float* __restrict__ W2, const float* __restrict__ W3, const float* __restrict__ W4,
    ushort* __restrict__ W2p, ushort* __restrict__ W3p, ushort* __restrict__ W4p) {
  const int blk = blockIdx.x;
  const int sel = blk / 384;
  const int bb = blk - sel * 384;
  const float* src = (sel == 0) ? W2 : (sel == 1) ? W3 : W4;
  ushort* dst = (sel == 0) ? W2p : (sel == 1) ? W3p : W4p;
  const int k = bb >> 4;
  const int co = ((bb & 15) << 3) + (threadIdx.x >> 5);
  const int cil = threadIdx.x & 31;
  #pragma unroll
  for (int c = 0; c < 4; ++c) {
    const float* sp = src + ((size_t)(k * 128 + co) * 128 + c * 32 + cil) * 9;
    float v[9];
    #pragma unroll
    for (int j = 0; j < 9; ++j) v[j] = sp[j];
    ushort* dp = dst + (size_t)(k * 4 + c) * 9 * 128 * 32;
    #pragma unroll
    for (int j = 0; j < 9; ++j) dp[(j * 128 + co) * 32 + cil] = f2bf(v[j]);
  }
}

// ---------------- fused capsule tower, 2 images per block ----------------
__device__ inline float tapf(const float* tm, int yi, int xi) {
  const bool ok = (xi >= 0) & (xi < 11) & (yi >= 0) & (yi < 11);
  const int yc = min(max(yi, 0), 10), xc = min(max(xi, 0), 10);
  const float v = tm[yc * 11 + xc];
  return ok ? v : 0.0f;
}

__global__ __launch_bounds__(256, 2) void k_tower(
    const float* __restrict__ x, const ushort* __restrict__ W1p,
    const ushort* __restrict__ W2p, const float* __restrict__ b2,
    const ushort* __restrict__ W3p, const float* __restrict__ b3,
    const ushort* __restrict__ W4p, const float* __restrict__ b4,
    const ushort* __restrict__ W5p, const float* __restrict__ b5,
    const float* __restrict__ noise, const float* __restrict__ templates,
    float* __restrict__ out, ushort* __restrict__ ttb,
    float* __restrict__ smax, float* __restrict__ sden, float* __restrict__ dmw)
{
  const int bi = blockIdx.x;
  const int blk = (bi & 7) * 192 + (bi >> 3);   // XCD swizzle (1536/8=192)
  const int kb0 = blk * 2;
  const int k = kb0 >> 7;
  const int b0 = kb0 & 127;
  const int t = threadIdx.x;

  __shared__ __align__(16) char R1[R1_SZ];
  __shared__ float red[8];
  __shared__ float b5s[24];
  __shared__ float tm[121];

  ushort* xim = (ushort*)(R1 + XIM_OFF);
  ushort* h1T = (ushort*)(R1 + H1T_OFF);
  ushort* xsb = (ushort*)(R1 + XSB_OFF);
  char* h2sb = R1 + H2S_OFF;
  char* h3sb = R1 + H3S_OFF;
  ushort* h4b = (ushort*)(R1 + H4B_OFF);
  float*  outs_s = (float*)(R1 + OUTS_OFF);
  float*  att_s  = (float*)(R1 + ATT_OFF);
  float*  ps  = (float*)(R1 + PS_OFF);

  // ---- stage x (both images) as bf16 ----
  for (int i = t; i < 800; i += 256) {
    const int im = i / 400, j = i - im * 400;
    const float4 v = ((const float4*)(x + (size_t)(b0 + im) * 1600))[j];
    uint2 pk;
    pk.x = cvtpk(v.x, v.y);
    pk.y = cvtpk(v.z, v.w);
    *(uint2*)(xsb + im * 1600 + 4 * j) = pk;
  }
  bar_lds();

  // ---- build xim [2][361][16] (taps 0..8, k9 = 1.0 for bias, zeros) ----
  for (int f = t; f < 722; f += 256) {
    const int im = f / 361, fl = f - im * 361;
    const int py = fl / 19, px = fl - 19 * py;
    const ushort* bp = xsb + im * 1600 + py * 80 + px * 2;
    const uint32 t0 = bp[0], t1 = bp[1], t2 = bp[2];
    const uint32 t3 = bp[40], t4 = bp[41], t5 = bp[42];
    const uint32 t6 = bp[80], t7 = bp[81], t8 = bp[82];
    uint4* dp = (uint4*)(xim + (im * 361 + fl) * 16);
    dp[0] = make_uint4(t0 | (t1 << 16), t2 | (t3 << 16), t4 | (t5 << 16), t6 | (t7 << 16));
    dp[1] = make_uint4(t8 | 0x3F800000u, 0u, 0u, 0u);   // k9 = 1.0 (bias lane)
  }

  const int w = t >> 6, lane = t & 63, r = lane & 15, s = lane >> 4;
  const int img = w >> 1;    // image this wave owns
  const int wi  = w & 1;     // wave-in-image (M split)
  const int m0  = wi * 64;

  ushort* xim_i = xim + img * 5776;
  ushort* h1T_i = h1T + img * 14440;
  char* h1Tb_i = (char*)h1T_i;
  char* h2s_i = h2sb + img * 25920;
  char* h3s_i = h3sb + img * 15680;
  ushort* h4b_i = h4b + img * 3400;

  // ================= conv1 + conv2 =================
  {
    int bb2[6];   // byte base into h1T_i for each N-tile (invalid -> 0)
    #pragma unroll
    for (int ni = 0; ni < 6; ++ni) {
      const int n = 16 * ni + r;
      const int py = n / 9, px = n - 9 * py;
      bb2[ni] = ((n < 81) ? (38 * py + 2 * px) * 80 : 0) + 16 * s;
    }

    f32x4 acc[4][6];
    #pragma unroll
    for (int mi = 0; mi < 4; ++mi)
      #pragma unroll
      for (int ni = 0; ni < 6; ++ni) acc[mi][ni] = (f32x4){0.f, 0.f, 0.f, 0.f};

    const ushort* W2k = W2p + (size_t)k * 147456 + (m0 + r) * 32 + 8 * s;
    const ushort* W1k = W1p + ((size_t)k * 128 + 16 * wi + r) * 32 + 8 * s;

    for (int c = 0; c < 4; ++c) {
      bar_lds();
      // conv1: co = 32c+16wi..+16, all 23 N-tiles (bias folded via k9)
      {
        const bf16x8 a1 = *(const bf16x8*)(W1k + c * 1024);
        const int cil0 = 16 * wi + 4 * s;
        const bf16x8 bz = {};
        #pragma unroll
        for (int nt = 0; nt < 23; ++nt) {
          const int n = nt * 16 + r;
          const int pos = (n < 361) ? n : 360;
          bf16x8 bv = *(const bf16x8*)(xim_i + pos * 16 + 8 * (s & 1));
          if (s >= 2) bv = bz;
          f32x4 cc = __builtin_amdgcn_mfma_f32_16x16x32_bf16(a1, bv, (f32x4){0.f, 0.f, 0.f, 0.f}, 0, 0, 0);
          if (n < 361) {
            uint2 pk;
            pk.x = cvtpk(fmaxf(cc[0], 0.f), fmaxf(cc[1], 0.f));
            pk.y = cvtpk(fmaxf(cc[2], 0.f), fmaxf(cc[3], 0.f));
            *(uint2*)(h1T_i + n * 40 + cil0) = pk;
          }
        }
      }
      bar_lds();
      // conv2: 9 taps in 3 groups of 3; SGB template pins 6-deep ds_read read-ahead
      const ushort* Abase = W2k + (size_t)c * 36864;
      bf16x8 Ag[2][12];
      #pragma unroll
      for (int q = 0; q < 12; ++q)
        Ag[0][q] = *(const bf16x8*)(Abase + (size_t)(q >> 2) * 4096 + (q & 3) * 512);
      #pragma unroll
      for (int g = 0; g < 3; ++g) {
        if (g < 2) {
          #pragma unroll
          for (int q = 0; q < 12; ++q)
            Ag[(g + 1) & 1][q] = *(const bf16x8*)(Abase + (size_t)(3 * (g + 1) + (q >> 2)) * 4096 + (q & 3) * 512);
        }
        #pragma unroll
        for (int jj = 0; jj < 3; ++jj) {
          bf16x8 Bv[6];
          #pragma unroll
          for (int ni = 0; ni < 6; ++ni)
            Bv[ni] = *(const bf16x8*)(h1Tb_i + bb2[ni] + (g * 19 + jj) * 80);
          if (g == 0 && jj == 0) __builtin_amdgcn_sched_group_barrier(0x100, 12, 0);
          __builtin_amdgcn_sched_group_barrier(0x8, 24, 0);
          #pragma unroll
          for (int mi = 0; mi < 4; ++mi)
            #pragma unroll
            for (int ni = 0; ni < 6; ++ni)
              acc[mi][ni] = __builtin_amdgcn_mfma_f32_16x16x32_bf16(Ag[g & 1][jj * 4 + mi], Bv[ni], acc[mi][ni], 0, 0, 0);
          if (!(g == 2 && jj >= 1)) __builtin_amdgcn_sched_group_barrier(0x100, 6, 0);
        }
      }
    }
    bar_lds();   // all conv2 reads done -> write h2s
    #pragma unroll
    for (int mi = 0; mi < 4; ++mi) {
      const int co0 = m0 + 16 * mi + 4 * s;
      const float4 bv = *(const float4*)(b2 + k * 128 + co0);
      const int c2 = co0 >> 5, cil = co0 & 31;
      #pragma unroll
      for (int ni = 0; ni < 6; ++ni) {
        const int p = 16 * ni + r;
        if (p < 81) {
          uint2 pk;
          pk.x = cvtpk(fmaxf(acc[mi][ni][0] + bv.x, 0.f), fmaxf(acc[mi][ni][1] + bv.y, 0.f));
          pk.y = cvtpk(fmaxf(acc[mi][ni][2] + bv.z, 0.f), fmaxf(acc[mi][ni][3] + bv.w, 0.f));
          *(uint2*)(h2s_i + ((c2 * 81 + p) * 40 + cil) * 2) = pk;
        }
      }
    }
  }
  bar_lds();

  // ================= conv3 =================
  {
    int bb3[4];
    #pragma unroll
    for (int ni = 0; ni < 4; ++ni) {
      const int n = 16 * ni + r;
      const int py = n / 7, px = n - 7 * py;
      bb3[ni] = ((n < 49) ? (9 * py + px) * 80 : 0) + 16 * s;
    }
    f32x4 acc[4][4];
    #pragma unroll
    for (int mi = 0; mi < 4; ++mi)
      #pragma unroll
      for (int ni = 0; ni < 4; ++ni) acc[mi][ni] = (f32x4){0.f, 0.f, 0.f, 0.f};

    const ushort* W3k = W3p + (size_t)k * 147456 + (m0 + r) * 32 + 8 * s;
    for (int c = 0; c < 4; ++c) {
      const ushort* Abase = W3k + (size_t)c * 36864;
      const char* h2c = h2s_i + c * 6480;
      bf16x8 Ag[2][12];
      #pragma unroll
      for (int q = 0; q < 12; ++q)
        Ag[0][q] = *(const bf16x8*)(Abase + (size_t)(q >> 2) * 4096 + (q & 3) * 512);
      #pragma unroll
      for (int g = 0; g < 3; ++g) {
        if (g < 2) {
          #pragma unroll
          for (int q = 0; q < 12; ++q)
            Ag[(g + 1) & 1][q] = *(const bf16x8*)(Abase + (size_t)(3 * (g + 1) + (q >> 2)) * 4096 + (q & 3) * 512);
        }
        #pragma unroll
        for (int jj = 0; jj < 3; ++jj) {
          bf16x8 Bv[4];
          #pragma unroll
          for (int ni = 0; ni < 4; ++ni)
            Bv[ni] = *(const bf16x8*)(h2c + bb3[ni] + (g * 9 + jj) * 80);
          if (g == 0 && jj == 0) __builtin_amdgcn_sched_group_barrier(0x100, 8, 0);
          __builtin_amdgcn_sched_group_barrier(0x8, 16, 0);
          #pragma unroll
          for (int mi = 0; mi < 4; ++mi)
            #pragma unroll
            for (int ni = 0; ni < 4; ++ni)
              acc[mi][ni] = __builtin_amdgcn_mfma_f32_16x16x32_bf16(Ag[g & 1][jj * 4 + mi], Bv[ni], acc[mi][ni], 0, 0, 0);
          if (!(g == 2 && jj >= 1)) __builtin_amdgcn_sched_group_barrier(0x100, 4, 0);
        }
      }
    }
    bar_lds();   // h2s dead -> write h3s; stage tm
    #pragma unroll
    for (int mi = 0; mi < 4; ++mi) {
      const int co0 = m0 + 16 * mi + 4 * s;
      const float4 bv = *(const float4*)(b3 + k * 128 + co0);
      const int c2 = co0 >> 5, cil = co0 & 31;
      #pragma unroll
      for (int ni = 0; ni < 4; ++ni) {
        const int p = 16 * ni + r;
        if (p < 49) {
          uint2 pk;
          pk.x = cvtpk(fmaxf(acc[mi][ni][0] + bv.x, 0.f), fmaxf(acc[mi][ni][1] + bv.y, 0.f));
          pk.y = cvtpk(fmaxf(acc[mi][ni][2] + bv.z, 0.f), fmaxf(acc[mi][ni][3] + bv.w, 0.f));
          *(uint2*)(h3s_i + ((c2 * 49 + p) * 40 + cil) * 2) = pk;
        }
      }
    }
    for (int i = t; i < 121; i += 256) tm[i] = templates[k * 121 + i];
  }
  bar_lds();

  // ================= conv4 =================
  {
    int bb4[2];
    #pragma unroll
    for (int ni = 0; ni < 2; ++ni) {
      const int n = 16 * ni + r;
      const int py = n / 5, px = n - 5 * py;
      bb4[ni] = ((n < 25) ? (7 * py + px) * 80 : 0) + 16 * s;
    }
    f32x4 acc[4][2];
    #pragma unroll
    for (int mi = 0; mi < 4; ++mi)
      #pragma unroll
      for (int ni = 0; ni < 2; ++ni) acc[mi][ni] = (f32x4){0.f, 0.f, 0.f, 0.f};

    const ushort* W4k = W4p + (size_t)k * 147456 + (m0 + r) * 32 + 8 * s;
    for (int c = 0; c < 4; ++c) {
      const ushort* Abase = W4k + (size_t)c * 36864;
      const char* h3c = h3s_i + c * 3920;
      bf16x8 Ag[2][12];
      #pragma unroll
      for (int q = 0; q < 12; ++q)
        Ag[0][q] = *(const bf16x8*)(Abase + (size_t)(q >> 2) * 4096 + (q & 3) * 512);
      #pragma unroll
      for (int g = 0; g < 3; ++g) {
        if (g < 2) {
          #pragma unroll
          for (int q = 0; q < 12; ++q)
            Ag[(g + 1) & 1][q] = *(const bf16x8*)(Abase + (size_t)(3 * (g + 1) + (q >> 2)) * 4096 + (q & 3) * 512);
        }
        #pragma unroll
        for (int jj = 0; jj < 3; ++jj) {
          bf16x8 Bv[2];
          #pragma unroll
          for (int ni = 0; ni < 2; ++ni)
            Bv[ni] = *(const bf16x8*)(h3c + bb4[ni] + (g * 7 + jj) * 80);
          if (g == 0 && jj == 0) __builtin_amdgcn_sched_group_barrier(0x100, 4, 0);
          __builtin_amdgcn_sched_group_barrier(0x8, 8, 0);
          #pragma unroll
          for (int mi = 0; mi < 4; ++mi)
            #pragma unroll
            for (int ni = 0; ni < 2; ++ni)
              acc[mi][ni] = __builtin_amdgcn_mfma_f32_16x16x32_bf16(Ag[g & 1][jj * 4 + mi], Bv[ni], acc[mi][ni], 0, 0, 0);
          if (!(g == 2 && jj >= 1)) __builtin_amdgcn_sched_group_barrier(0x100, 2, 0);
        }
      }
    }
    bar_lds();   // h3s dead -> write h4b (bf16, [p][136]); stage b5s
    #pragma unroll
    for (int mi = 0; mi < 4; ++mi) {
      const int co0 = m0 + 16 * mi + 4 * s;
      const float4 bv = *(const float4*)(b4 + k * 128 + co0);
      #pragma unroll
      for (int ni = 0; ni < 2; ++ni) {
        const int p = 16 * ni + r;
        if (p < 25) {
          uint2 pk;
          pk.x = cvtpk(fmaxf(acc[mi][ni][0] + bv.x, 0.f), fmaxf(acc[mi][ni][1] + bv.y, 0.f));
          pk.y = cvtpk(fmaxf(acc[mi][ni][2] + bv.z, 0.f), fmaxf(acc[mi][ni][3] + bv.w, 0.f));
          *(uint2*)(h4b_i + p * 136 + co0) = pk;
        }
      }
    }
    if (t < 24) b5s[t] = b5[k * 24 + t];
  }
  bar_lds();

  // ================= conv5 via MFMA (M=32pad, N=25, K=128) =================
  {
    const int mt = wi;
    f32x4 acc5[2];
    acc5[0] = (f32x4){0.f, 0.f, 0.f, 0.f};
    acc5[1] = (f32x4){0.f, 0.f, 0.f, 0.f};
    const ushort* A5 = W5p + ((size_t)k * 32 + mt * 16 + r) * 128 + 8 * s;
    #pragma unroll
    for (int ks = 0; ks < 4; ++ks) {
      const bf16x8 a5 = *(const bf16x8*)(A5 + ks * 32);
      #pragma unroll
      for (int nt = 0; nt < 2; ++nt) {
        const int p = 16 * nt + r;
        const int pv = (p < 25) ? p : 0;
        const bf16x8 bv = *(const bf16x8*)(h4b_i + pv * 136 + ks * 32 + 8 * s);
        acc5[nt] = __builtin_amdgcn_mfma_f32_16x16x32_bf16(a5, bv, acc5[nt], 0, 0, 0);
      }
    }
    #pragma unroll
    for (int nt = 0; nt < 2; ++nt) {
      const int p = 16 * nt + r;
      if (p < 25) {
        #pragma unroll
        for (int rg = 0; rg < 4; ++rg) {
          const int fm = mt * 16 + 4 * s + rg;
          if (fm < 24) outs_s[img * 600 + fm * 25 + p] = acc5[nt][rg] + b5s[fm];
        }
      }
    }
  }
  bar_lds();

  // ================= att softmax (wave 0 -> img0, wave 2 -> img1) =================
  if (!(t & 64)) {
    const int im = t >> 7;
    const int tl = t & 63;
    float v = (tl < 25) ? outs_s[im * 600 + 575 + tl] : -1e30f;
    #pragma unroll
    for (int off = 32; off; off >>= 1) v = fmaxf(v, __shfl_xor(v, off));
    const float m = v;
    float e = (tl < 25) ? expf(outs_s[im * 600 + 575 + tl] - m) : 0.0f;
    float ss = e;
    #pragma unroll
    for (int off = 32; off; off >>= 1) ss += __shfl_xor(ss, off);
    if (tl < 25) att_s[im * 25 + tl] = e / ss;
  }
  bar_lds();

  // ================= pool =================
  {
    const int im = t >> 7;
    const int tl = t & 127;
    if (tl < 23) {
      float v = 0.f;
      #pragma unroll
      for (int p = 0; p < 25; ++p) v = fmaf(outs_s[im * 600 + tl * 25 + p], att_s[im * 25 + p], v);
      ps[im * 23 + tl] = v;
    }
  }
  bar_lds();

  // ================= pose + warp + softmax stats =================
  float dmv[2];
  #pragma unroll
  for (int im = 0; im < 2; ++im) {
    const int idx = (b0 + im) * KK + k;
    const float dl = ps[im * 23 + 6] + noise[idx];
    dmv[im] = 1.0f / (1.0f + expf(-dl));
  }

  #pragma unroll
  for (int im = 0; im < 2; ++im) {
    const int idx = (b0 + im) * KK + k;
    if (t < 144) {
      float v;
      if (t == 0)       v = dmv[im];
      else if (t < 7)   v = fmaxf(ps[im * 23 + t - 1], 0.0f);
      else if (t < 128) v = tm[t - 7];
      else              v = fmaxf(ps[im * 23 + 7 + (t - 128)], 0.0f);
      out[O_OCAE + (size_t)idx * 144 + t] = v;
    }
    if (t < 6) out[O_XM + (size_t)idx * 6 + t] = fmaxf(ps[im * 23 + t], 0.0f);
    if (t == 0) out[O_DM + idx] = dmv[im];
  }

  const int im = t >> 7;
  const int tl = t & 127;
  const int idx = (b0 + im) * KK + k;
  const float dm = dmv[im];

  const float D2R = 0.017453292519943295f;
  const float ang = fmaxf(ps[im * 23 + 0], 0.0f) * D2R;
  const float tx = fmaxf(ps[im * 23 + 1], 0.0f), ty = fmaxf(ps[im * 23 + 2], 0.0f);
  const float sc = fmaxf(ps[im * 23 + 3], 0.0f) + 1e-6f;
  const float sxr = fmaxf(ps[im * 23 + 4], 0.0f) * D2R;
  const float syr = fmaxf(ps[im * 23 + 5], 0.0f) * D2R;
  const float cas = cosf(ang - syr), sas = sinf(ang - syr);
  const float csy = cosf(syr), tsx = tanf(sxr);
  const float a_ = cas / csy;
  const float b_ = -cas * tsx / csy - sinf(ang);
  const float c_ = sas / csy;
  const float d_ = -sas * tsx / csy + cosf(ang);
  const float m00 = d_ / sc, m01 = -b_ / sc, m10 = -c_ / sc, m11 = a_ / sc;
  const float m02 = m00 * (-5.0f - tx) + m01 * (-5.0f - ty) + 5.0f;
  const float m12 = m10 * (-5.0f - tx) + m11 * (-5.0f - ty) + 5.0f;

  const float S = 0.275f;
  float ttv[13];
  float lmax = -1e30f;
  #pragma unroll
  for (int i = 0; i < 13; ++i) {
    const int pix = tl + 128 * i;
    float val2 = 0.0f;
    if (pix < 1600) {
      const int py = pix / 40, px = pix - 40 * py;
      const float u = (px + 0.5f) * S - 0.5f;
      const float v = (py + 0.5f) * S - 0.5f;
      const float sx = m00 * u + m01 * v + m02;
      const float sy = m10 * u + m11 * v + m12;
      const float x0 = floorf(sx), y0 = floorf(sy);
      const float wx = sx - x0, wy = sy - y0;
      const int xi = (int)x0, yi = (int)y0;
      const float v00 = tapf(tm, yi, xi);
      const float v01 = tapf(tm, yi, xi + 1);
      const float v10 = tapf(tm, yi + 1, xi);
      const float v11 = tapf(tm, yi + 1, xi + 1);
      const float val = (v00 * (1.0f - wx) + v01 * wx) * (1.0f - wy) + (v10 * (1.0f - wx) + v11 * wx) * wy;
      const ushort tb = f2bf(val);
      val2 = bf2f(tb);
      ttb[(size_t)idx * 1600 + pix] = tb;
      lmax = fmaxf(lmax, dm * val2);
    }
    ttv[i] = val2;
  }

  #pragma unroll
  for (int off = 32; off; off >>= 1) lmax = fmaxf(lmax, __shfl_xor(lmax, off));
  if ((t & 63) == 0) red[t >> 6] = lmax;
  bar_lds();
  const float m = fmaxf(red[2 * im], red[2 * im + 1]);
  float ls = 0.0f;
  #pragma unroll
  for (int i = 0; i < 13; ++i)
    if (tl + 128 * i < 1600) ls += expf(fmaf(dm, ttv[i], -m));
  #pragma unroll
  for (int off = 32; off; off >>= 1) ls += __shfl_xor(ls, off);
  bar_lds();
  if ((t & 63) == 0) red[4 + (t >> 6)] = ls;
  bar_lds();
  if ((t & 127) == 0) {
    smax[idx] = m;
    sden[idx] = red[4 + 2 * im] + red[5 + 2 * im];
    dmw[idx] = dm;
  }
}

// ---------------- per-pixel mixture + log ----------------
__global__ __launch_bounds__(256) void k_ll(
    const float* __restrict__ x, const ushort* __restrict__ ttb,
    const float* __restrict__ smax, const float* __restrict__ sden,
    const float* __restrict__ dmw, float* __restrict__ part)
{
  const int b = blockIdx.x >> 2;
  const int chunk = blockIdx.x & 3;
  const int t = threadIdx.x;

  __shared__ __align__(16) float xs[1600];
  __shared__ float kd[24], km[24], ki[24];
  __shared__ float red[4], red2[4];

  for (int i = t; i < 400; i += 256)
    ((float4*)xs)[i] = ((const float4*)(x + (size_t)b * 1600))[i];
  if (t < 24) {
    kd[t] = dmw[b * 24 + t];
    km[t] = smax[b * 24 + t];
    ki[t] = 1.0f / sden[b * 24 + t];
  }
  __syncthreads();

  float s1 = 0.f, s2 = 0.f;
  for (int i = t; i < 1600; i += 256) { const float v = xs[i]; s1 += v; s2 = fmaf(v, v, s2); }
  #pragma unroll
  for (int off = 32; off; off >>= 1) { s1 += __shfl_xor(s1, off); s2 += __shfl_xor(s2, off); }
  if ((t & 63) == 0) { red[t >> 6] = s1; red2[t >> 6] = s2; }
  __syncthreads();
  s1 = red[0] + red[1] + red[2] + red[3];
  s2 = red2[0] + red2[1] + red2[2] + red2[3];
  const float var = (s2 - s1 * s1 * (1.0f / 1600.0f)) * (1.0f / 1599.0f);
  const float stdv = sqrtf(var);
  const float mult = 1.0f / sqrtf(stdv * 6.283185307179586f);
  const float pmul = -1.0f / (2.0f * stdv * stdv);

  const int p0 = chunk * 400;
  float ll = 0.0f;
  for (int ii = t; ii < 400; ii += 256) {
    const int pix = p0 + ii;
    const float xv = xs[pix];
    float sum = 0.0f;
    #pragma unroll 6
    for (int kk2 = 0; kk2 < 24; ++kk2) {
      const float tv = bf2f(ttb[(size_t)(b * 24 + kk2) * 1600 + pix]);
      const float dxv = xv - tv;
      sum += expf(fmaf(dxv * dxv, pmul, fmaf(kd[kk2], tv, -km[kk2]))) * ki[kk2];
    }
    ll += logf(mult * sum);
  }
  #pragma unroll
  for (int off = 32; off; off >>= 1) ll += __shfl_xor(ll, off);
  __syncthreads();
  if ((t & 63) == 0) red[t >> 6] = ll;
  __syncthreads();
  if (t == 0) part[blockIdx.x] = red[0] + red[1] + red[2] + red[3];
}

__global__ void k_final(const float* __restrict__ part, float* __restrict__ out)
{
  const int t = threadIdx.x;
  float v = part[t] + part[t + 256];
  #pragma unroll
  for (int off = 32; off; off >>= 1) v += __shfl_xor(v, off);
  __shared__ float red[4];
  if ((t & 63) == 0) red[t >> 6] = v;
  __syncthreads();
  if (t == 0) out[0] = (red[0] + red[1] + red[2] + red[3]) * (1.0f / 128.0f);
}

extern "C" void kernel_launch(void* const* d_in, const int* in_sizes, int n_in,
                              void* d_out, int out_size, void* d_ws, size_t ws_size,
                              hipStream_t stream)
{
  const float* x     = (const float*)d_in[0];
  const float* noise = (const float*)d_in[1];
  const float* W1    = (const float*)d_in[2];
  const float* b1    = (const float*)d_in[3];
  const float* W2    = (const float*)d_in[4];
  const float* b2    = (const float*)d_in[5];
  const float* W3    = (const float*)d_in[6];
  const float* b3    = (const float*)d_in[7];
  const float* W4    = (const float*)d_in[8];
  const float* b4    = (const float*)d_in[9];
  const float* W5    = (const float*)d_in[10];
  const float* b5    = (const float*)d_in[11];
  const float* tmpl  = (const float*)d_in[12];
  float* out = (float*)d_out;
  char* wsb = (char*)d_ws;

  ushort* W1p = (ushort*)(wsb + OFF_W1P);
  ushort* W5p = (ushort*)(wsb + OFF_W5P);
  ushort* W2p = (ushort*)(wsb + OFF_WB2);
  ushort* W3p = (ushort*)(wsb + OFF_WB3);
  ushort* W4p = (ushort*)(wsb + OFF_WB4);
  ushort* ttp  = (ushort*)(wsb + OFF_TT);
  float* smaxp = (float*)(wsb + OFF_SMAX);
  float* sdenp = (float*)(wsb + OFF_SDEN);
  float* dmp   = (float*)(wsb + OFF_DM);
  float* partp = (float*)(wsb + OFF_PART);

  k_w1p<<<24, 128, 0, stream>>>(W1, W5, b1, W1p, W5p);
  k_wp<<<1152, 256, 0, stream>>>(W2, W3, W4, W2p, W3p, W4p);
  k_tower<<<KK * BB / 2, 256, 0, stream>>>(x, W1p, W2p, b2, W3p, b3, W4p, b4,
                                           W5p, b5, noise, tmpl, out, ttp, smaxp, sdenp, dmp);
  k_ll<<<BB * 4, 256, 0, stream>>>(x, ttp, smaxp, sdenp, dmp, partp);
  k_final<<<1, 256, 0, stream>>>(partp, out);
}

// Round 13
// 242.455 us; speedup vs baseline: 1.7246x; 1.7246x over previous
//
#include <hip/hip_runtime.h>
#include <math.h>

typedef __attribute__((ext_vector_type(8))) short bf16x8;
typedef __attribute__((ext_vector_type(4))) float f32x4;
typedef __attribute__((ext_vector_type(16))) float f32x16;
typedef unsigned int uint32;
typedef unsigned short ushort;

namespace {
constexpr int KK = 24, BB = 128;

constexpr size_t SZ_W1P = (size_t)24 * 128 * 32 * 2;
constexpr size_t SZ_W5P = (size_t)24 * 32 * 128 * 2;
constexpr size_t SZ_WB  = (size_t)24 * 128 * 1152 * 2;
constexpr size_t OFF_W1P = 0;
constexpr size_t OFF_W5P = OFF_W1P + SZ_W1P;
constexpr size_t OFF_WB2 = OFF_W5P + SZ_W5P;
constexpr size_t OFF_WB3 = OFF_WB2 + SZ_WB;
constexpr size_t OFF_WB4 = OFF_WB3 + SZ_WB;
constexpr size_t OFF_TT  = OFF_WB4 + SZ_WB;      // bf16 tt
constexpr size_t SZ_TT   = (size_t)128 * 24 * 1600 * 2;
constexpr size_t OFF_SMAX = OFF_TT + SZ_TT;
constexpr size_t OFF_SDEN = OFF_SMAX + 12288;
constexpr size_t OFF_DM   = OFF_SDEN + 12288;
constexpr size_t OFF_PART = OFF_DM + 12288;

constexpr long long O_OCAE = 1;
constexpr long long O_XM   = O_OCAE + (long long)BB * KK * 144;
constexpr long long O_DM   = O_XM + (long long)BB * KK * 6;

// ---- phase-aliased LDS (byte offsets into R1); 2 images per block ----
constexpr int R1_SZ   = 80864;
constexpr int XIM_OFF = 0;       // ush [2][361][16] = 23,104
constexpr int H1T_OFF = 23104;   // ush [2][361][40] = 57,760 -> 80,864
constexpr int XSB_OFF = 74464;   // ush [2][1600] (tail of h1T img1; dead before conv1)
constexpr int H2S_OFF = 0;       // ush [2][4][81][40] = 51,840
constexpr int H3S_OFF = 0;       // ush [2][4][49][40] = 31,360
constexpr int H4B_OFF = 31392;   // ush [2][25][136] = 13,600 -> 44,992
constexpr int OUTS_OFF = 0;      // f32 [2][600] = 4,800
constexpr int ATT_OFF = 4800;    // f32 [2][25]
constexpr int PS_OFF  = 5000;    // f32 [2][23] -> 5,184
}

__device__ inline ushort f2bf(float f) {
  uint32 u = __builtin_bit_cast(uint32, f);
  u += 0x7fffu + ((u >> 16) & 1u);
  return (ushort)(u >> 16);
}
__device__ inline float bf2f(ushort u) {
  return __builtin_bit_cast(float, (uint32)u << 16);
}
__device__ inline uint32 cvtpk(float a, float b) {
  uint32 r;
  asm("v_cvt_pk_bf16_f32 %0, %1, %2" : "=v"(r) : "v"(a), "v"(b));
  return r;
}
// LDS-only barrier: drains LDS ops but leaves global loads in flight (no vmcnt(0)).
__device__ inline void bar_lds() {
  asm volatile("s_waitcnt lgkmcnt(0)\n\ts_barrier" ::: "memory");
}

// ---------------- weight permutes ----------------
// W1p[k][co][32] with k=9 slot = b1 (bias folded via xim k9=1.0); W5p[k][fm(32,pad0)][128]
__global__ __launch_bounds__(128) void k_w1p(const float* __restrict__ W1,
                                             const float* __restrict__ W5,
                                             const float* __restrict__ b1,
                                             ushort* __restrict__ W1p,
                                             ushort* __restrict__ W5p) {
  const int k = blockIdx.x, t = threadIdx.x;
  {
    ushort tmp[32];
    #pragma unroll
    for (int i = 0; i < 32; ++i) tmp[i] = 0;
    #pragma unroll
    for (int j = 0; j < 9; ++j) tmp[j] = f2bf(W1[(k * 128 + t) * 9 + j]);
    tmp[9] = f2bf(b1[k * 128 + t]);
    uint4* dp = (uint4*)(W1p + ((size_t)k * 128 + t) * 32);
    #pragma unroll
    for (int i = 0; i < 4; ++i) dp[i] = ((uint4*)tmp)[i];
  }
  if (t < 32) {
    ushort* dp = W5p + ((size_t)k * 32 + t) * 128;
    if (t < 24) {
      const float* sp = W5 + (size_t)k * 3072 + t * 128;
      for (int ci = 0; ci < 128; ++ci) dp[ci] = f2bf(sp[ci]);
    } else {
      for (int ci = 0; ci < 128; ++ci) dp[ci] = 0;
    }
  }
}

__global__ __launch_bounds__(256) void k_wp(
    const float* __restrict__ W2, const float* __restrict__ W3, const float* __restrict__ W4,
    ushort* __restrict__ W2p, ushort* __restrict__ W3p, ushort* __restrict__ W4p) {
  const int blk = blockIdx.x;
  const int sel = blk / 384;
  const int bb = blk - sel * 384;
  const float* src = (sel == 0) ? W2 : (sel == 1) ? W3 : W4;
  ushort* dst = (sel == 0) ? W2p : (sel == 1) ? W3p : W4p;
  const int k = bb >> 4;
  const int co = ((bb & 15) << 3) + (threadIdx.x >> 5);
  const int cil = threadIdx.x & 31;
  #pragma unroll
  for (int c = 0; c < 4; ++c) {
    const float* sp = src + ((size_t)(k * 128 + co) * 128 + c * 32 + cil) * 9;
    float v[9];
    #pragma unroll
    for (int j = 0; j < 9; ++j) v[j] = sp[j];
    ushort* dp = dst + (size_t)(k * 4 + c) * 9 * 128 * 32;
    #pragma unroll
    for (int j = 0; j < 9; ++j) dp[(j * 128 + co) * 32 + cil] = f2bf(v[j]);
  }
}

// ---------------- fused capsule tower, 2 images per block ----------------
__device__ inline float tapf(const float* tm, int yi, int xi) {
  const bool ok = (xi >= 0) & (xi < 11) & (yi >= 0) & (yi < 11);
  const int yc = min(max(yi, 0), 10), xc = min(max(xi, 0), 10);
  const float v = tm[yc * 11 + xc];
  return ok ? v : 0.0f;
}

__global__ __launch_bounds__(256, 2) void k_tower(
    const float* __restrict__ x, const ushort* __restrict__ W1p,
    const ushort* __restrict__ W2p, const float* __restrict__ b2,
    const ushort* __restrict__ W3p, const float* __restrict__ b3,
    const ushort* __restrict__ W4p, const float* __restrict__ b4,
    const ushort* __restrict__ W5p, const float* __restrict__ b5,
    const float* __restrict__ noise, const float* __restrict__ templates,
    float* __restrict__ out, ushort* __restrict__ ttb,
    float* __restrict__ smax, float* __restrict__ sden, float* __restrict__ dmw)
{
  const int bi = blockIdx.x;
  const int blk = (bi & 7) * 192 + (bi >> 3);   // XCD swizzle (1536/8=192)
  const int kb0 = blk * 2;
  const int k = kb0 >> 7;
  const int b0 = kb0 & 127;
  const int t = threadIdx.x;

  __shared__ __align__(16) char R1[R1_SZ];
  __shared__ float red[8];
  __shared__ float b5s[24];
  __shared__ float tm[121];

  ushort* xim = (ushort*)(R1 + XIM_OFF);
  ushort* h1T = (ushort*)(R1 + H1T_OFF);
  ushort* xsb = (ushort*)(R1 + XSB_OFF);
  char* h2sb = R1 + H2S_OFF;
  char* h3sb = R1 + H3S_OFF;
  ushort* h4b = (ushort*)(R1 + H4B_OFF);
  float*  outs_s = (float*)(R1 + OUTS_OFF);
  float*  att_s  = (float*)(R1 + ATT_OFF);
  float*  ps  = (float*)(R1 + PS_OFF);

  // ---- stage x (both images) as bf16 ----
  for (int i = t; i < 800; i += 256) {
    const int im = i / 400, j = i - im * 400;
    const float4 v = ((const float4*)(x + (size_t)(b0 + im) * 1600))[j];
    uint2 pk;
    pk.x = cvtpk(v.x, v.y);
    pk.y = cvtpk(v.z, v.w);
    *(uint2*)(xsb + im * 1600 + 4 * j) = pk;
  }
  bar_lds();

  // ---- build xim [2][361][16] (taps 0..8, k9 = 1.0 for bias, zeros) ----
  for (int f = t; f < 722; f += 256) {
    const int im = f / 361, fl = f - im * 361;
    const int py = fl / 19, px = fl - 19 * py;
    const ushort* bp = xsb + im * 1600 + py * 80 + px * 2;
    const uint32 t0 = bp[0], t1 = bp[1], t2 = bp[2];
    const uint32 t3 = bp[40], t4 = bp[41], t5 = bp[42];
    const uint32 t6 = bp[80], t7 = bp[81], t8 = bp[82];
    uint4* dp = (uint4*)(xim + (im * 361 + fl) * 16);
    dp[0] = make_uint4(t0 | (t1 << 16), t2 | (t3 << 16), t4 | (t5 << 16), t6 | (t7 << 16));
    dp[1] = make_uint4(t8 | 0x3F800000u, 0u, 0u, 0u);   // k9 = 1.0 (bias lane)
  }

  const int w = t >> 6, lane = t & 63, r = lane & 15, s = lane >> 4;
  const int l31 = lane & 31, kh = lane >> 5;   // 32x32 fragment coords
  const int img = w >> 1;    // image this wave owns
  const int wi  = w & 1;     // wave-in-image (M split)
  const int m0  = wi * 64;

  ushort* xim_i = xim + img * 5776;
  ushort* h1T_i = h1T + img * 14440;
  char* h1Tb_i = (char*)h1T_i;
  char* h2s_i = h2sb + img * 25920;
  char* h3s_i = h3sb + img * 15680;
  ushort* h4b_i = h4b + img * 3400;

  // ================= conv1 (16x16x32) + conv2 (32x32x16) =================
  {
    int bb2[3];   // byte base into h1T_i for each 32-wide N-tile
    #pragma unroll
    for (int nt = 0; nt < 3; ++nt) {
      const int n = 32 * nt + l31;
      const int py = n / 9, px = n - 9 * py;
      bb2[nt] = ((n < 81) ? (38 * py + 2 * px) * 80 : 0) + 16 * kh;
    }

    f32x16 acc[2][3];
    #pragma unroll
    for (int mt = 0; mt < 2; ++mt)
      #pragma unroll
      for (int nt = 0; nt < 3; ++nt) acc[mt][nt] = (f32x16)(0.f);

    // A base: row = m0 + 32*mt + l31, k-octet = kh
    const ushort* W2k = W2p + (size_t)k * 147456 + (m0 + l31) * 32 + 8 * kh;
    const ushort* W1k = W1p + ((size_t)k * 128 + 16 * wi + r) * 32 + 8 * s;

    for (int c = 0; c < 4; ++c) {
      bar_lds();
      // conv1: co = 32c+16wi..+16, all 23 N-tiles (bias folded via k9)
      {
        const bf16x8 a1 = *(const bf16x8*)(W1k + c * 1024);
        const int cil0 = 16 * wi + 4 * s;
        const bf16x8 bz = {};
        #pragma unroll
        for (int nt = 0; nt < 23; ++nt) {
          const int n = nt * 16 + r;
          const int pos = (n < 361) ? n : 360;
          bf16x8 bv = *(const bf16x8*)(xim_i + pos * 16 + 8 * (s & 1));
          if (s >= 2) bv = bz;
          f32x4 cc = __builtin_amdgcn_mfma_f32_16x16x32_bf16(a1, bv, (f32x4){0.f, 0.f, 0.f, 0.f}, 0, 0, 0);
          if (n < 361) {
            uint2 pk;
            pk.x = cvtpk(fmaxf(cc[0], 0.f), fmaxf(cc[1], 0.f));
            pk.y = cvtpk(fmaxf(cc[2], 0.f), fmaxf(cc[3], 0.f));
            *(uint2*)(h1T_i + n * 40 + cil0) = pk;
          }
        }
      }
      bar_lds();
      // conv2: 9 taps x 2 ci-halves (K=16 each), A groups of 12 double-buffered
      const ushort* Abase = W2k + (size_t)c * 36864;
      bf16x8 Ag[2][12];   // q = jj*4 + h*2 + mt
      #pragma unroll
      for (int q = 0; q < 12; ++q)
        Ag[0][q] = *(const bf16x8*)(Abase + (size_t)(q >> 2) * 4096 + (q & 1) * 1024 + ((q >> 1) & 1) * 16);
      #pragma unroll
      for (int g = 0; g < 3; ++g) {
        if (g < 2) {
          #pragma unroll
          for (int q = 0; q < 12; ++q)
            Ag[(g + 1) & 1][q] = *(const bf16x8*)(Abase + (size_t)(3 * (g + 1) + (q >> 2)) * 4096 + (q & 1) * 1024 + ((q >> 1) & 1) * 16);
        }
        #pragma unroll
        for (int jj = 0; jj < 3; ++jj) {
          const int j = 3 * g + jj;
          const int off80 = ((j / 3) * 19 + (j - 3 * (j / 3))) * 80;
          bf16x8 Bv[2][3];
          #pragma unroll
          for (int h = 0; h < 2; ++h)
            #pragma unroll
            for (int nt = 0; nt < 3; ++nt)
              Bv[h][nt] = *(const bf16x8*)(h1Tb_i + bb2[nt] + off80 + 32 * h);
          #pragma unroll
          for (int h = 0; h < 2; ++h)
            #pragma unroll
            for (int mt = 0; mt < 2; ++mt)
              #pragma unroll
              for (int nt = 0; nt < 3; ++nt)
                acc[mt][nt] = __builtin_amdgcn_mfma_f32_32x32x16_bf16(
                    Ag[g & 1][jj * 4 + h * 2 + mt], Bv[h][nt], acc[mt][nt], 0, 0, 0);
        }
      }
    }
    bar_lds();   // all conv2 reads done -> write h2s
    #pragma unroll
    for (int mt = 0; mt < 2; ++mt)
      #pragma unroll
      for (int nt = 0; nt < 3; ++nt) {
        const int p = 32 * nt + l31;
        if (p < 81) {
          #pragma unroll
          for (int q = 0; q < 4; ++q) {
            const int co0 = m0 + 32 * mt + 8 * q + 4 * kh;
            const float4 bv = *(const float4*)(b2 + k * 128 + co0);
            const int c2 = co0 >> 5, cil = co0 & 31;
            uint2 pk;
            pk.x = cvtpk(fmaxf(acc[mt][nt][4 * q + 0] + bv.x, 0.f), fmaxf(acc[mt][nt][4 * q + 1] + bv.y, 0.f));
            pk.y = cvtpk(fmaxf(acc[mt][nt][4 * q + 2] + bv.z, 0.f), fmaxf(acc[mt][nt][4 * q + 3] + bv.w, 0.f));
            *(uint2*)(h2s_i + ((c2 * 81 + p) * 40 + cil) * 2) = pk;
          }
        }
      }
  }
  bar_lds();

  // ================= conv3 (32x32x16) =================
  {
    int bb3[2];
    #pragma unroll
    for (int nt = 0; nt < 2; ++nt) {
      const int n = 32 * nt + l31;
      const int py = n / 7, px = n - 7 * py;
      bb3[nt] = ((n < 49) ? (9 * py + px) * 80 : 0) + 16 * kh;
    }
    f32x16 acc[2][2];
    #pragma unroll
    for (int mt = 0; mt < 2; ++mt)
      #pragma unroll
      for (int nt = 0; nt < 2; ++nt) acc[mt][nt] = (f32x16)(0.f);

    const ushort* W3k = W3p + (size_t)k * 147456 + (m0 + l31) * 32 + 8 * kh;
    for (int c = 0; c < 4; ++c) {
      const ushort* Abase = W3k + (size_t)c * 36864;
      const char* h2c = h2s_i + c * 6480;
      bf16x8 Ag[2][12];
      #pragma unroll
      for (int q = 0; q < 12; ++q)
        Ag[0][q] = *(const bf16x8*)(Abase + (size_t)(q >> 2) * 4096 + (q & 1) * 1024 + ((q >> 1) & 1) * 16);
      #pragma unroll
      for (int g = 0; g < 3; ++g) {
        if (g < 2) {
          #pragma unroll
          for (int q = 0; q < 12; ++q)
            Ag[(g + 1) & 1][q] = *(const bf16x8*)(Abase + (size_t)(3 * (g + 1) + (q >> 2)) * 4096 + (q & 1) * 1024 + ((q >> 1) & 1) * 16);
        }
        #pragma unroll
        for (int jj = 0; jj < 3; ++jj) {
          const int j = 3 * g + jj;
          const int off80 = ((j / 3) * 9 + (j - 3 * (j / 3))) * 80;
          bf16x8 Bv[2][2];
          #pragma unroll
          for (int h = 0; h < 2; ++h)
            #pragma unroll
            for (int nt = 0; nt < 2; ++nt)
              Bv[h][nt] = *(const bf16x8*)(h2c + bb3[nt] + off80 + 32 * h);
          #pragma unroll
          for (int h = 0; h < 2; ++h)
            #pragma unroll
            for (int mt = 0; mt < 2; ++mt)
              #pragma unroll
              for (int nt = 0; nt < 2; ++nt)
                acc[mt][nt] = __builtin_amdgcn_mfma_f32_32x32x16_bf16(
                    Ag[g & 1][jj * 4 + h * 2 + mt], Bv[h][nt], acc[mt][nt], 0, 0, 0);
        }
      }
    }
    bar_lds();   // h2s dead -> write h3s; stage tm
    #pragma unroll
    for (int mt = 0; mt < 2; ++mt)
      #pragma unroll
      for (int nt = 0; nt < 2; ++nt) {
        const int p = 32 * nt + l31;
        if (p < 49) {
          #pragma unroll
          for (int q = 0; q < 4; ++q) {
            const int co0 = m0 + 32 * mt + 8 * q + 4 * kh;
            const float4 bv = *(const float4*)(b3 + k * 128 + co0);
            const int c2 = co0 >> 5, cil = co0 & 31;
            uint2 pk;
            pk.x = cvtpk(fmaxf(acc[mt][nt][4 * q + 0] + bv.x, 0.f), fmaxf(acc[mt][nt][4 * q + 1] + bv.y, 0.f));
            pk.y = cvtpk(fmaxf(acc[mt][nt][4 * q + 2] + bv.z, 0.f), fmaxf(acc[mt][nt][4 * q + 3] + bv.w, 0.f));
            *(uint2*)(h3s_i + ((c2 * 49 + p) * 40 + cil) * 2) = pk;
          }
        }
      }
    for (int i = t; i < 121; i += 256) tm[i] = templates[k * 121 + i];
  }
  bar_lds();

  // ================= conv4 (32x32x16) =================
  {
    const int n4 = l31;
    const int py4 = n4 / 5, px4 = n4 - 5 * py4;
    const int bb4 = ((n4 < 25) ? (7 * py4 + px4) * 80 : 0) + 16 * kh;
    f32x16 acc[2];
    acc[0] = (f32x16)(0.f);
    acc[1] = (f32x16)(0.f);

    const ushort* W4k = W4p + (size_t)k * 147456 + (m0 + l31) * 32 + 8 * kh;
    for (int c = 0; c < 4; ++c) {
      const ushort* Abase = W4k + (size_t)c * 36864;
      const char* h3c = h3s_i + c * 3920;
      bf16x8 Ag[2][12];
      #pragma unroll
      for (int q = 0; q < 12; ++q)
        Ag[0][q] = *(const bf16x8*)(Abase + (size_t)(q >> 2) * 4096 + (q & 1) * 1024 + ((q >> 1) & 1) * 16);
      #pragma unroll
      for (int g = 0; g < 3; ++g) {
        if (g < 2) {
          #pragma unroll
          for (int q = 0; q < 12; ++q)
            Ag[(g + 1) & 1][q] = *(const bf16x8*)(Abase + (size_t)(3 * (g + 1) + (q >> 2)) * 4096 + (q & 1) * 1024 + ((q >> 1) & 1) * 16);
        }
        #pragma unroll
        for (int jj = 0; jj < 3; ++jj) {
          const int j = 3 * g + jj;
          const int off80 = ((j / 3) * 7 + (j - 3 * (j / 3))) * 80;
          bf16x8 Bv[2];
          #pragma unroll
          for (int h = 0; h < 2; ++h)
            Bv[h] = *(const bf16x8*)(h3c + bb4 + off80 + 32 * h);
          #pragma unroll
          for (int h = 0; h < 2; ++h)
            #pragma unroll
            for (int mt = 0; mt < 2; ++mt)
              acc[mt] = __builtin_amdgcn_mfma_f32_32x32x16_bf16(
                  Ag[g & 1][jj * 4 + h * 2 + mt], Bv[h], acc[mt], 0, 0, 0);
        }
      }
    }
    bar_lds();   // h3s dead -> write h4b (bf16, [p][136]); stage b5s
    #pragma unroll
    for (int mt = 0; mt < 2; ++mt) {
      const int p = l31;
      if (p < 25) {
        #pragma unroll
        for (int q = 0; q < 4; ++q) {
          const int co0 = m0 + 32 * mt + 8 * q + 4 * kh;
          const float4 bv = *(const float4*)(b4 + k * 128 + co0);
          uint2 pk;
          pk.x = cvtpk(fmaxf(acc[mt][4 * q + 0] + bv.x, 0.f), fmaxf(acc[mt][4 * q + 1] + bv.y, 0.f));
          pk.y = cvtpk(fmaxf(acc[mt][4 * q + 2] + bv.z, 0.f), fmaxf(acc[mt][4 * q + 3] + bv.w, 0.f));
          *(uint2*)(h4b_i + p * 136 + co0) = pk;
        }
      }
    }
    if (t < 24) b5s[t] = b5[k * 24 + t];
  }
  bar_lds();

  // ================= conv5 via MFMA (16x16x32; M=32pad, N=25, K=128) =================
  {
    const int mt = wi;
    f32x4 acc5[2];
    acc5[0] = (f32x4){0.f, 0.f, 0.f, 0.f};
    acc5[1] = (f32x4){0.f, 0.f, 0.f, 0.f};
    const ushort* A5 = W5p + ((size_t)k * 32 + mt * 16 + r) * 128 + 8 * s;
    #pragma unroll
    for (int ks = 0; ks < 4; ++ks) {
      const bf16x8 a5 = *(const bf16x8*)(A5 + ks * 32);
      #pragma unroll
      for (int nt = 0; nt < 2; ++nt) {
        const int p = 16 * nt + r;
        const int pv = (p < 25) ? p : 0;
        const bf16x8 bv = *(const bf16x8*)(h4b_i + pv * 136 + ks * 32 + 8 * s);
        acc5[nt] = __builtin_amdgcn_mfma_f32_16x16x32_bf16(a5, bv, acc5[nt], 0, 0, 0);
      }
    }
    #pragma unroll
    for (int nt = 0; nt < 2; ++nt) {
      const int p = 16 * nt + r;
      if (p < 25) {
        #pragma unroll
        for (int rg = 0; rg < 4; ++rg) {
          const int fm = mt * 16 + 4 * s + rg;
          if (fm < 24) outs_s[img * 600 + fm * 25 + p] = acc5[nt][rg] + b5s[fm];
        }
      }
    }
  }
  bar_lds();

  // ================= att softmax (wave 0 -> img0, wave 2 -> img1) =================
  if (!(t & 64)) {
    const int im = t >> 7;
    const int tl = t & 63;
    float v = (tl < 25) ? outs_s[im * 600 + 575 + tl] : -1e30f;
    #pragma unroll
    for (int off = 32; off; off >>= 1) v = fmaxf(v, __shfl_xor(v, off));
    const float m = v;
    float e = (tl < 25) ? expf(outs_s[im * 600 + 575 + tl] - m) : 0.0f;
    float ss = e;
    #pragma unroll
    for (int off = 32; off; off >>= 1) ss += __shfl_xor(ss, off);
    if (tl < 25) att_s[im * 25 + tl] = e / ss;
  }
  bar_lds();

  // ================= pool =================
  {
    const int im = t >> 7;
    const int tl = t & 127;
    if (tl < 23) {
      float v = 0.f;
      #pragma unroll
      for (int p = 0; p < 25; ++p) v = fmaf(outs_s[im * 600 + tl * 25 + p], att_s[im * 25 + p], v);
      ps[im * 23 + tl] = v;
    }
  }
  bar_lds();

  // ================= pose + warp + softmax stats =================
  float dmv[2];
  #pragma unroll
  for (int im = 0; im < 2; ++im) {
    const int idx = (b0 + im) * KK + k;
    const float dl = ps[im * 23 + 6] + noise[idx];
    dmv[im] = 1.0f / (1.0f + expf(-dl));
  }

  #pragma unroll
  for (int im = 0; im < 2; ++im) {
    const int idx = (b0 + im) * KK + k;
    if (t < 144) {
      float v;
      if (t == 0)       v = dmv[im];
      else if (t < 7)   v = fmaxf(ps[im * 23 + t - 1], 0.0f);
      else if (t < 128) v = tm[t - 7];
      else              v = fmaxf(ps[im * 23 + 7 + (t - 128)], 0.0f);
      out[O_OCAE + (size_t)idx * 144 + t] = v;
    }
    if (t < 6) out[O_XM + (size_t)idx * 6 + t] = fmaxf(ps[im * 23 + t], 0.0f);
    if (t == 0) out[O_DM + idx] = dmv[im];
  }

  const int im = t >> 7;
  const int tl = t & 127;
  const int idx = (b0 + im) * KK + k;
  const float dm = dmv[im];

  const float D2R = 0.017453292519943295f;
  const float ang = fmaxf(ps[im * 23 + 0], 0.0f) * D2R;
  const float tx = fmaxf(ps[im * 23 + 1], 0.0f), ty = fmaxf(ps[im * 23 + 2], 0.0f);
  const float sc = fmaxf(ps[im * 23 + 3], 0.0f) + 1e-6f;
  const float sxr = fmaxf(ps[im * 23 + 4], 0.0f) * D2R;
  const float syr = fmaxf(ps[im * 23 + 5], 0.0f) * D2R;
  const float cas = cosf(ang - syr), sas = sinf(ang - syr);
  const float csy = cosf(syr), tsx = tanf(sxr);
  const float a_ = cas / csy;
  const float b_ = -cas * tsx / csy - sinf(ang);
  const float c_ = sas / csy;
  const float d_ = -sas * tsx / csy + cosf(ang);
  const float m00 = d_ / sc, m01 = -b_ / sc, m10 = -c_ / sc, m11 = a_ / sc;
  const float m02 = m00 * (-5.0f - tx) + m01 * (-5.0f - ty) + 5.0f;
  const float m12 = m10 * (-5.0f - tx) + m11 * (-5.0f - ty) + 5.0f;

  const float S = 0.275f;
  float ttv[13];
  float lmax = -1e30f;
  #pragma unroll
  for (int i = 0; i < 13; ++i) {
    const int pix = tl + 128 * i;
    float val2 = 0.0f;
    if (pix < 1600) {
      const int py = pix / 40, px = pix - 40 * py;
      const float u = (px + 0.5f) * S - 0.5f;
      const float v = (py + 0.5f) * S - 0.5f;
      const float sx = m00 * u + m01 * v + m02;
      const float sy = m10 * u + m11 * v + m12;
      const float x0 = floorf(sx), y0 = floorf(sy);
      const float wx = sx - x0, wy = sy - y0;
      const int xi = (int)x0, yi = (int)y0;
      const float v00 = tapf(tm, yi, xi);
      const float v01 = tapf(tm, yi, xi + 1);
      const float v10 = tapf(tm, yi + 1, xi);
      const float v11 = tapf(tm, yi + 1, xi + 1);
      const float val = (v00 * (1.0f - wx) + v01 * wx) * (1.0f - wy) + (v10 * (1.0f - wx) + v11 * wx) * wy;
      const ushort tb = f2bf(val);
      val2 = bf2f(tb);
      ttb[(size_t)idx * 1600 + pix] = tb;
      lmax = fmaxf(lmax, dm * val2);
    }
    ttv[i] = val2;
  }

  #pragma unroll
  for (int off = 32; off; off >>= 1) lmax = fmaxf(lmax, __shfl_xor(lmax, off));
  if ((t & 63) == 0) red[t >> 6] = lmax;
  bar_lds();
  const float m = fmaxf(red[2 * im], red[2 * im + 1]);
  float ls = 0.0f;
  #pragma unroll
  for (int i = 0; i < 13; ++i)
    if (tl + 128 * i < 1600) ls += expf(fmaf(dm, ttv[i], -m));
  #pragma unroll
  for (int off = 32; off; off >>= 1) ls += __shfl_xor(ls, off);
  bar_lds();
  if ((t & 63) == 0) red[4 + (t >> 6)] = ls;
  bar_lds();
  if ((t & 127) == 0) {
    smax[idx] = m;
    sden[idx] = red[4 + 2 * im] + red[5 + 2 * im];
    dmw[idx] = dm;
  }
}

// ---------------- per-pixel mixture + log ----------------
__global__ __launch_bounds__(256) void k_ll(
    const float* __restrict__ x, const ushort* __restrict__ ttb,
    const float* __restrict__ smax, const float* __restrict__ sden,
    const float* __restrict__ dmw, float* __restrict__ part)
{
  const int b = blockIdx.x >> 2;
  const int chunk = blockIdx.x & 3;
  const int t = threadIdx.x;

  __shared__ __align__(16) float xs[1600];
  __shared__ float kd[24], km[24], ki[24];
  __shared__ float red[4], red2[4];

  for (int i = t; i < 400; i += 256)
    ((float4*)xs)[i] = ((const float4*)(x + (size_t)b * 1600))[i];
  if (t < 24) {
    kd[t] = dmw[b * 24 + t];
    km[t] = smax[b * 24 + t];
    ki[t] = 1.0f / sden[b * 24 + t];
  }
  __syncthreads();

  float s1 = 0.f, s2 = 0.f;
  for (int i = t; i < 1600; i += 256) { const float v = xs[i]; s1 += v; s2 = fmaf(v, v, s2); }
  #pragma unroll
  for (int off = 32; off; off >>= 1) { s1 += __shfl_xor(s1, off); s2 += __shfl_xor(s2, off); }
  if ((t & 63) == 0) { red[t >> 6] = s1; red2[t >> 6] = s2; }
  __syncthreads();
  s1 = red[0] + red[1] + red[2] + red[3];
  s2 = red2[0] + red2[1] + red2[2] + red2[3];
  const float var = (s2 - s1 * s1 * (1.0f / 1600.0f)) * (1.0f / 1599.0f);
  const float stdv = sqrtf(var);
  const float mult = 1.0f / sqrtf(stdv * 6.283185307179586f);
  const float pmul = -1.0f / (2.0f * stdv * stdv);

  const int p0 = chunk * 400;
  float ll = 0.0f;
  for (int ii = t; ii < 400; ii += 256) {
    const int pix = p0 + ii;
    const float xv = xs[pix];
    float sum = 0.0f;
    #pragma unroll 6
    for (int kk2 = 0; kk2 < 24; ++kk2) {
      const float tv = bf2f(ttb[(size_t)(b * 24 + kk2) * 1600 + pix]);
      const float dxv = xv - tv;
      sum += expf(fmaf(dxv * dxv, pmul, fmaf(kd[kk2], tv, -km[kk2]))) * ki[kk2];
    }
    ll += logf(mult * sum);
  }
  #pragma unroll
  for (int off = 32; off; off >>= 1) ll += __shfl_xor(ll, off);
  __syncthreads();
  if ((t & 63) == 0) red[t >> 6] = ll;
  __syncthreads();
  if (t == 0) part[blockIdx.x] = red[0] + red[1] + red[2] + red[3];
}

__global__ void k_final(const float* __restrict__ part, float* __restrict__ out)
{
  const int t = threadIdx.x;
  float v = part[t] + part[t + 256];
  #pragma unroll
  for (int off = 32; off; off >>= 1) v += __shfl_xor(v, off);
  __shared__ float red[4];
  if ((t & 63) == 0) red[t >> 6] = v;
  __syncthreads();
  if (t == 0) out[0] = (red[0] + red[1] + red[2] + red[3]) * (1.0f / 128.0f);
}

extern "C" void kernel_launch(void* const* d_in, const int* in_sizes, int n_in,
                              void* d_out, int out_size, void* d_ws, size_t ws_size,
                              hipStream_t stream)
{
  const float* x     = (const float*)d_in[0];
  const float* noise = (const float*)d_in[1];
  const float* W1    = (const float*)d_in[2];
  const float* b1    = (const float*)d_in[3];
  const float* W2    = (const float*)d_in[4];
  const float* b2    = (const float*)d_in[5];
  const float* W3    = (const float*)d_in[6];
  const float* b3    = (const float*)d_in[7];
  const float* W4    = (const float*)d_in[8];
  const float* b4    = (const float*)d_in[9];
  const float* W5    = (const float*)d_in[10];
  const float* b5    = (const float*)d_in[11];
  const float* tmpl  = (const float*)d_in[12];
  float* out = (float*)d_out;
  char* wsb = (char*)d_ws;

  ushort* W1p = (ushort*)(wsb + OFF_W1P);
  ushort* W5p = (ushort*)(wsb + OFF_W5P);
  ushort* W2p = (ushort*)(wsb + OFF_WB2);
  ushort* W3p = (ushort*)(wsb + OFF_WB3);
  ushort* W4p = (ushort*)(wsb + OFF_WB4);
  ushort* ttp  = (ushort*)(wsb + OFF_TT);
  float* smaxp = (float*)(wsb + OFF_SMAX);
  float* sdenp = (float*)(wsb + OFF_SDEN);
  float* dmp   = (float*)(wsb + OFF_DM);
  float* partp = (float*)(wsb + OFF_PART);

  k_w1p<<<24, 128, 0, stream>>>(W1, W5, b1, W1p, W5p);
  k_wp<<<1152, 256, 0, stream>>>(W2, W3, W4, W2p, W3p, W4p);
  k_tower<<<KK * BB / 2, 256, 0, stream>>>(x, W1p, W2p, b2, W3p, b3, W4p, b4,
                                           W5p, b5, noise, tmpl, out, ttp, smaxp, sdenp, dmp);
  k_ll<<<BB * 4, 256, 0, stream>>>(x, ttp, smaxp, sdenp, dmp, partp);
  k_final<<<1, 256, 0, stream>>>(partp, out);
}

// Round 14
// 232.951 us; speedup vs baseline: 1.7949x; 1.0408x over previous
//
#include <hip/hip_runtime.h>
#include <math.h>

typedef __attribute__((ext_vector_type(8))) short bf16x8;
typedef __attribute__((ext_vector_type(4))) float f32x4;
typedef __attribute__((ext_vector_type(16))) float f32x16;
typedef unsigned int uint32;
typedef unsigned short ushort;

namespace {
constexpr int KK = 24, BB = 128;

constexpr size_t SZ_W1P = (size_t)24 * 128 * 32 * 2;
constexpr size_t SZ_W5P = (size_t)24 * 32 * 128 * 2;
constexpr size_t SZ_WB  = (size_t)24 * 128 * 1152 * 2;
constexpr size_t OFF_W1P = 0;
constexpr size_t OFF_W5P = OFF_W1P + SZ_W1P;
constexpr size_t OFF_WB2 = OFF_W5P + SZ_W5P;
constexpr size_t OFF_WB3 = OFF_WB2 + SZ_WB;
constexpr size_t OFF_WB4 = OFF_WB3 + SZ_WB;
constexpr size_t OFF_TT  = OFF_WB4 + SZ_WB;      // bf16 tt
constexpr size_t SZ_TT   = (size_t)128 * 24 * 1600 * 2;
constexpr size_t OFF_SMAX = OFF_TT + SZ_TT;
constexpr size_t OFF_SDEN = OFF_SMAX + 12288;
constexpr size_t OFF_DM   = OFF_SDEN + 12288;
constexpr size_t OFF_PART = OFF_DM + 12288;

constexpr long long O_OCAE = 1;
constexpr long long O_XM   = O_OCAE + (long long)BB * KK * 144;
constexpr long long O_DM   = O_XM + (long long)BB * KK * 6;

// ---- phase-aliased LDS (byte offsets into R1); 2 images per block ----
constexpr int R1_SZ   = 80864;
constexpr int XIM_OFF = 0;       // ush [2][361][16] = 23,104
constexpr int H1T_OFF = 23104;   // ush [2][361][40] = 57,760 -> 80,864
constexpr int XSB_OFF = 74464;   // ush [2][1600] (tail of h1T img1; dead before conv1)
constexpr int H2S_OFF = 0;       // ush [2][4][81][40] = 51,840
constexpr int H3S_OFF = 0;       // ush [2][4][49][40] = 31,360
constexpr int H4B_OFF = 31392;   // ush [2][25][136] = 13,600 -> 44,992
constexpr int OUTS_OFF = 0;      // f32 [2][600] = 4,800
constexpr int ATT_OFF = 4800;    // f32 [2][25]
constexpr int PS_OFF  = 5000;    // f32 [2][23] -> 5,184
}

__device__ inline ushort f2bf(float f) {
  uint32 u = __builtin_bit_cast(uint32, f);
  u += 0x7fffu + ((u >> 16) & 1u);
  return (ushort)(u >> 16);
}
__device__ inline float bf2f(ushort u) {
  return __builtin_bit_cast(float, (uint32)u << 16);
}
__device__ inline uint32 cvtpk(float a, float b) {
  uint32 r;
  asm("v_cvt_pk_bf16_f32 %0, %1, %2" : "=v"(r) : "v"(a), "v"(b));
  return r;
}
// LDS-only barrier: drains LDS ops but leaves global loads in flight (no vmcnt(0)).
__device__ inline void bar_lds() {
  asm volatile("s_waitcnt lgkmcnt(0)\n\ts_barrier" ::: "memory");
}

// ---------------- weight permutes ----------------
// W1p[k][co][32] with k=9 slot = b1 (bias folded via xim k9=1.0); W5p[k][fm(32,pad0)][128]
__global__ __launch_bounds__(128) void k_w1p(const float* __restrict__ W1,
                                             const float* __restrict__ W5,
                                             const float* __restrict__ b1,
                                             ushort* __restrict__ W1p,
                                             ushort* __restrict__ W5p) {
  const int k = blockIdx.x, t = threadIdx.x;
  {
    ushort tmp[32];
    #pragma unroll
    for (int i = 0; i < 32; ++i) tmp[i] = 0;
    #pragma unroll
    for (int j = 0; j < 9; ++j) tmp[j] = f2bf(W1[(k * 128 + t) * 9 + j]);
    tmp[9] = f2bf(b1[k * 128 + t]);
    uint4* dp = (uint4*)(W1p + ((size_t)k * 128 + t) * 32);
    #pragma unroll
    for (int i = 0; i < 4; ++i) dp[i] = ((uint4*)tmp)[i];
  }
  if (t < 32) {
    ushort* dp = W5p + ((size_t)k * 32 + t) * 128;
    if (t < 24) {
      const float* sp = W5 + (size_t)k * 3072 + t * 128;
      for (int ci = 0; ci < 128; ++ci) dp[ci] = f2bf(sp[ci]);
    } else {
      for (int ci = 0; ci < 128; ++ci) dp[ci] = 0;
    }
  }
}

__global__ __launch_bounds__(256) void k_wp(
    const float* __restrict__ W2, const float* __restrict__ W3, const float* __restrict__ W4,
    ushort* __restrict__ W2p, ushort* __restrict__ W3p, ushort* __restrict__ W4p) {
  const int blk = blockIdx.x;
  const int sel = blk / 384;
  const int bb = blk - sel * 384;
  const float* src = (sel == 0) ? W2 : (sel == 1) ? W3 : W4;
  ushort* dst = (sel == 0) ? W2p : (sel == 1) ? W3p : W4p;
  const int k = bb >> 4;
  const int co = ((bb & 15) << 3) + (threadIdx.x >> 5);
  const int cil = threadIdx.x & 31;
  #pragma unroll
  for (int c = 0; c < 4; ++c) {
    const float* sp = src + ((size_t)(k * 128 + co) * 128 + c * 32 + cil) * 9;
    float v[9];
    #pragma unroll
    for (int j = 0; j < 9; ++j) v[j] = sp[j];
    ushort* dp = dst + (size_t)(k * 4 + c) * 9 * 128 * 32;
    #pragma unroll
    for (int j = 0; j < 9; ++j) dp[(j * 128 + co) * 32 + cil] = f2bf(v[j]);
  }
}

// ---------------- fused capsule tower, 2 images per block ----------------
__device__ inline float tapf(const float* tm, int yi, int xi) {
  const bool ok = (xi >= 0) & (xi < 11) & (yi >= 0) & (yi < 11);
  const int yc = min(max(yi, 0), 10), xc = min(max(xi, 0), 10);
  const float v = tm[yc * 11 + xc];
  return ok ? v : 0.0f;
}

__global__ __launch_bounds__(256, 2) void k_tower(
    const float* __restrict__ x, const ushort* __restrict__ W1p,
    const ushort* __restrict__ W2p, const float* __restrict__ b2,
    const ushort* __restrict__ W3p, const float* __restrict__ b3,
    const ushort* __restrict__ W4p, const float* __restrict__ b4,
    const ushort* __restrict__ W5p, const float* __restrict__ b5,
    const float* __restrict__ noise, const float* __restrict__ templates,
    float* __restrict__ out, ushort* __restrict__ ttb,
    float* __restrict__ smax, float* __restrict__ sden, float* __restrict__ dmw)
{
  const int bi = blockIdx.x;
  const int blk = (bi & 7) * 192 + (bi >> 3);   // XCD swizzle (1536/8=192)
  const int kb0 = blk * 2;
  const int k = kb0 >> 7;
  const int b0 = kb0 & 127;
  const int t = threadIdx.x;

  __shared__ __align__(16) char R1[R1_SZ];
  __shared__ float red[8];
  __shared__ float b5s[24];
  __shared__ float tm[121];

  ushort* xim = (ushort*)(R1 + XIM_OFF);
  ushort* h1T = (ushort*)(R1 + H1T_OFF);
  ushort* xsb = (ushort*)(R1 + XSB_OFF);
  char* h2sb = R1 + H2S_OFF;
  char* h3sb = R1 + H3S_OFF;
  ushort* h4b = (ushort*)(R1 + H4B_OFF);
  float*  outs_s = (float*)(R1 + OUTS_OFF);
  float*  att_s  = (float*)(R1 + ATT_OFF);
  float*  ps  = (float*)(R1 + PS_OFF);

  // ---- stage x (both images) as bf16 ----
  for (int i = t; i < 800; i += 256) {
    const int im = i / 400, j = i - im * 400;
    const float4 v = ((const float4*)(x + (size_t)(b0 + im) * 1600))[j];
    uint2 pk;
    pk.x = cvtpk(v.x, v.y);
    pk.y = cvtpk(v.z, v.w);
    *(uint2*)(xsb + im * 1600 + 4 * j) = pk;
  }
  bar_lds();

  // ---- build xim [2][361][16] (taps 0..8, k9 = 1.0 for bias, zeros) ----
  for (int f = t; f < 722; f += 256) {
    const int im = f / 361, fl = f - im * 361;
    const int py = fl / 19, px = fl - 19 * py;
    const ushort* bp = xsb + im * 1600 + py * 80 + px * 2;
    const uint32 t0 = bp[0], t1 = bp[1], t2 = bp[2];
    const uint32 t3 = bp[40], t4 = bp[41], t5 = bp[42];
    const uint32 t6 = bp[80], t7 = bp[81], t8 = bp[82];
    uint4* dp = (uint4*)(xim + (im * 361 + fl) * 16);
    dp[0] = make_uint4(t0 | (t1 << 16), t2 | (t3 << 16), t4 | (t5 << 16), t6 | (t7 << 16));
    dp[1] = make_uint4(t8 | 0x3F800000u, 0u, 0u, 0u);   // k9 = 1.0 (bias lane)
  }

  const int w = t >> 6, lane = t & 63, r = lane & 15, s = lane >> 4;
  const int l31 = lane & 31, kh = lane >> 5;   // 32x32 fragment coords
  const int img = w >> 1;    // image this wave owns
  const int wi  = w & 1;     // wave-in-image (M split)
  const int m0  = wi * 64;

  ushort* xim_i = xim + img * 5776;
  ushort* h1T_i = h1T + img * 14440;
  char* h1Tb_i = (char*)h1T_i;
  char* h2s_i = h2sb + img * 25920;
  char* h3s_i = h3sb + img * 15680;
  ushort* h4b_i = h4b + img * 3400;

  // ================= conv1 (32x32x16) + conv2 (32x32x16) =================
  {
    int bb2[3];   // byte base into h1T_i for each 32-wide N-tile
    #pragma unroll
    for (int nt = 0; nt < 3; ++nt) {
      const int n = 32 * nt + l31;
      const int py = n / 9, px = n - 9 * py;
      bb2[nt] = ((n < 81) ? (38 * py + 2 * px) * 80 : 0) + 16 * kh;
    }

    f32x16 acc[2][3];
    #pragma unroll
    for (int mt = 0; mt < 2; ++mt)
      #pragma unroll
      for (int nt = 0; nt < 3; ++nt) acc[mt][nt] = (f32x16)(0.f);

    // A base: row = m0 + 32*mt + l31, k-octet = kh
    const ushort* W2k = W2p + (size_t)k * 147456 + (m0 + l31) * 32 + 8 * kh;
    const ushort* W1k = W1p + ((size_t)k * 128 + l31) * 32 + 8 * kh;

    for (int c = 0; c < 4; ++c) {
      bar_lds();
      // conv1 via 32x32x16: co chunk = 32c..32c+31 (M=32), N split 6 tiles/wave
      {
        const bf16x8 a1 = *(const bf16x8*)(W1k + c * 1024);
        #pragma unroll
        for (int nt2 = 0; nt2 < 6; ++nt2) {
          const int n = (wi * 6 + nt2) * 32 + l31;
          const int pos = (n < 361) ? n : 360;
          const bf16x8 bv = *(const bf16x8*)(xim_i + pos * 16 + 8 * kh);
          f32x16 cc = __builtin_amdgcn_mfma_f32_32x32x16_bf16(a1, bv, (f32x16)(0.f), 0, 0, 0);
          if (n < 361) {
            #pragma unroll
            for (int q = 0; q < 4; ++q) {
              const int cil = 8 * q + 4 * kh;
              uint2 pk;
              pk.x = cvtpk(fmaxf(cc[4 * q + 0], 0.f), fmaxf(cc[4 * q + 1], 0.f));
              pk.y = cvtpk(fmaxf(cc[4 * q + 2], 0.f), fmaxf(cc[4 * q + 3], 0.f));
              *(uint2*)(h1T_i + n * 40 + cil) = pk;
            }
          }
        }
      }
      bar_lds();
      // conv2: 9 taps x 2 ci-halves (K=16 each), A groups of 12 double-buffered
      const ushort* Abase = W2k + (size_t)c * 36864;
      bf16x8 Ag[2][12];   // q = jj*4 + h*2 + mt
      #pragma unroll
      for (int q = 0; q < 12; ++q)
        Ag[0][q] = *(const bf16x8*)(Abase + (size_t)(q >> 2) * 4096 + (q & 1) * 1024 + ((q >> 1) & 1) * 16);
      #pragma unroll
      for (int g = 0; g < 3; ++g) {
        if (g < 2) {
          #pragma unroll
          for (int q = 0; q < 12; ++q)
            Ag[(g + 1) & 1][q] = *(const bf16x8*)(Abase + (size_t)(3 * (g + 1) + (q >> 2)) * 4096 + (q & 1) * 1024 + ((q >> 1) & 1) * 16);
        }
        #pragma unroll
        for (int jj = 0; jj < 3; ++jj) {
          const int j = 3 * g + jj;
          const int off80 = ((j / 3) * 19 + (j - 3 * (j / 3))) * 80;
          bf16x8 Bv[2][3];
          #pragma unroll
          for (int h = 0; h < 2; ++h)
            #pragma unroll
            for (int nt = 0; nt < 3; ++nt)
              Bv[h][nt] = *(const bf16x8*)(h1Tb_i + bb2[nt] + off80 + 32 * h);
          #pragma unroll
          for (int h = 0; h < 2; ++h)
            #pragma unroll
            for (int mt = 0; mt < 2; ++mt)
              #pragma unroll
              for (int nt = 0; nt < 3; ++nt)
                acc[mt][nt] = __builtin_amdgcn_mfma_f32_32x32x16_bf16(
                    Ag[g & 1][jj * 4 + h * 2 + mt], Bv[h][nt], acc[mt][nt], 0, 0, 0);
        }
      }
    }
    bar_lds();   // all conv2 reads done -> write h2s
    #pragma unroll
    for (int mt = 0; mt < 2; ++mt)
      #pragma unroll
      for (int nt = 0; nt < 3; ++nt) {
        const int p = 32 * nt + l31;
        if (p < 81) {
          #pragma unroll
          for (int q = 0; q < 4; ++q) {
            const int co0 = m0 + 32 * mt + 8 * q + 4 * kh;
            const float4 bv = *(const float4*)(b2 + k * 128 + co0);
            const int c2 = co0 >> 5, cil = co0 & 31;
            uint2 pk;
            pk.x = cvtpk(fmaxf(acc[mt][nt][4 * q + 0] + bv.x, 0.f), fmaxf(acc[mt][nt][4 * q + 1] + bv.y, 0.f));
            pk.y = cvtpk(fmaxf(acc[mt][nt][4 * q + 2] + bv.z, 0.f), fmaxf(acc[mt][nt][4 * q + 3] + bv.w, 0.f));
            *(uint2*)(h2s_i + ((c2 * 81 + p) * 40 + cil) * 2) = pk;
          }
        }
      }
  }
  bar_lds();

  // ================= conv3 (32x32x16) =================
  {
    int bb3[2];
    #pragma unroll
    for (int nt = 0; nt < 2; ++nt) {
      const int n = 32 * nt + l31;
      const int py = n / 7, px = n - 7 * py;
      bb3[nt] = ((n < 49) ? (9 * py + px) * 80 : 0) + 16 * kh;
    }
    f32x16 acc[2][2];
    #pragma unroll
    for (int mt = 0; mt < 2; ++mt)
      #pragma unroll
      for (int nt = 0; nt < 2; ++nt) acc[mt][nt] = (f32x16)(0.f);

    const ushort* W3k = W3p + (size_t)k * 147456 + (m0 + l31) * 32 + 8 * kh;
    for (int c = 0; c < 4; ++c) {
      const ushort* Abase = W3k + (size_t)c * 36864;
      const char* h2c = h2s_i + c * 6480;
      bf16x8 Ag[2][12];
      #pragma unroll
      for (int q = 0; q < 12; ++q)
        Ag[0][q] = *(const bf16x8*)(Abase + (size_t)(q >> 2) * 4096 + (q & 1) * 1024 + ((q >> 1) & 1) * 16);
      #pragma unroll
      for (int g = 0; g < 3; ++g) {
        if (g < 2) {
          #pragma unroll
          for (int q = 0; q < 12; ++q)
            Ag[(g + 1) & 1][q] = *(const bf16x8*)(Abase + (size_t)(3 * (g + 1) + (q >> 2)) * 4096 + (q & 1) * 1024 + ((q >> 1) & 1) * 16);
        }
        #pragma unroll
        for (int jj = 0; jj < 3; ++jj) {
          const int j = 3 * g + jj;
          const int off80 = ((j / 3) * 9 + (j - 3 * (j / 3))) * 80;
          bf16x8 Bv[2][2];
          #pragma unroll
          for (int h = 0; h < 2; ++h)
            #pragma unroll
            for (int nt = 0; nt < 2; ++nt)
              Bv[h][nt] = *(const bf16x8*)(h2c + bb3[nt] + off80 + 32 * h);
          #pragma unroll
          for (int h = 0; h < 2; ++h)
            #pragma unroll
            for (int mt = 0; mt < 2; ++mt)
              #pragma unroll
              for (int nt = 0; nt < 2; ++nt)
                acc[mt][nt] = __builtin_amdgcn_mfma_f32_32x32x16_bf16(
                    Ag[g & 1][jj * 4 + h * 2 + mt], Bv[h][nt], acc[mt][nt], 0, 0, 0);
        }
      }
    }
    bar_lds();   // h2s dead -> write h3s; stage tm
    #pragma unroll
    for (int mt = 0; mt < 2; ++mt)
      #pragma unroll
      for (int nt = 0; nt < 2; ++nt) {
        const int p = 32 * nt + l31;
        if (p < 49) {
          #pragma unroll
          for (int q = 0; q < 4; ++q) {
            const int co0 = m0 + 32 * mt + 8 * q + 4 * kh;
            const float4 bv = *(const float4*)(b3 + k * 128 + co0);
            const int c2 = co0 >> 5, cil = co0 & 31;
            uint2 pk;
            pk.x = cvtpk(fmaxf(acc[mt][nt][4 * q + 0] + bv.x, 0.f), fmaxf(acc[mt][nt][4 * q + 1] + bv.y, 0.f));
            pk.y = cvtpk(fmaxf(acc[mt][nt][4 * q + 2] + bv.z, 0.f), fmaxf(acc[mt][nt][4 * q + 3] + bv.w, 0.f));
            *(uint2*)(h3s_i + ((c2 * 49 + p) * 40 + cil) * 2) = pk;
          }
        }
      }
    for (int i = t; i < 121; i += 256) tm[i] = templates[k * 121 + i];
  }
  bar_lds();

  // ================= conv4 (32x32x16) =================
  {
    const int n4 = l31;
    const int py4 = n4 / 5, px4 = n4 - 5 * py4;
    const int bb4 = ((n4 < 25) ? (7 * py4 + px4) * 80 : 0) + 16 * kh;
    f32x16 acc[2];
    acc[0] = (f32x16)(0.f);
    acc[1] = (f32x16)(0.f);

    const ushort* W4k = W4p + (size_t)k * 147456 + (m0 + l31) * 32 + 8 * kh;
    for (int c = 0; c < 4; ++c) {
      const ushort* Abase = W4k + (size_t)c * 36864;
      const char* h3c = h3s_i + c * 3920;
      bf16x8 Ag[2][12];
      #pragma unroll
      for (int q = 0; q < 12; ++q)
        Ag[0][q] = *(const bf16x8*)(Abase + (size_t)(q >> 2) * 4096 + (q & 1) * 1024 + ((q >> 1) & 1) * 16);
      #pragma unroll
      for (int g = 0; g < 3; ++g) {
        if (g < 2) {
          #pragma unroll
          for (int q = 0; q < 12; ++q)
            Ag[(g + 1) & 1][q] = *(const bf16x8*)(Abase + (size_t)(3 * (g + 1) + (q >> 2)) * 4096 + (q & 1) * 1024 + ((q >> 1) & 1) * 16);
        }
        #pragma unroll
        for (int jj = 0; jj < 3; ++jj) {
          const int j = 3 * g + jj;
          const int off80 = ((j / 3) * 7 + (j - 3 * (j / 3))) * 80;
          bf16x8 Bv[2];
          #pragma unroll
          for (int h = 0; h < 2; ++h)
            Bv[h] = *(const bf16x8*)(h3c + bb4 + off80 + 32 * h);
          #pragma unroll
          for (int h = 0; h < 2; ++h)
            #pragma unroll
            for (int mt = 0; mt < 2; ++mt)
              acc[mt] = __builtin_amdgcn_mfma_f32_32x32x16_bf16(
                  Ag[g & 1][jj * 4 + h * 2 + mt], Bv[h], acc[mt], 0, 0, 0);
        }
      }
    }
    bar_lds();   // h3s dead -> write h4b (bf16, [p][136]); stage b5s
    #pragma unroll
    for (int mt = 0; mt < 2; ++mt) {
      const int p = l31;
      if (p < 25) {
        #pragma unroll
        for (int q = 0; q < 4; ++q) {
          const int co0 = m0 + 32 * mt + 8 * q + 4 * kh;
          const float4 bv = *(const float4*)(b4 + k * 128 + co0);
          uint2 pk;
          pk.x = cvtpk(fmaxf(acc[mt][4 * q + 0] + bv.x, 0.f), fmaxf(acc[mt][4 * q + 1] + bv.y, 0.f));
          pk.y = cvtpk(fmaxf(acc[mt][4 * q + 2] + bv.z, 0.f), fmaxf(acc[mt][4 * q + 3] + bv.w, 0.f));
          *(uint2*)(h4b_i + p * 136 + co0) = pk;
        }
      }
    }
    if (t < 24) b5s[t] = b5[k * 24 + t];
  }
  bar_lds();

  // ================= conv5 via MFMA (16x16x32; M=32pad, N=25, K=128) =================
  {
    const int mt = wi;
    f32x4 acc5[2];
    acc5[0] = (f32x4){0.f, 0.f, 0.f, 0.f};
    acc5[1] = (f32x4){0.f, 0.f, 0.f, 0.f};
    const ushort* A5 = W5p + ((size_t)k * 32 + mt * 16 + r) * 128 + 8 * s;
    #pragma unroll
    for (int ks = 0; ks < 4; ++ks) {
      const bf16x8 a5 = *(const bf16x8*)(A5 + ks * 32);
      #pragma unroll
      for (int nt = 0; nt < 2; ++nt) {
        const int p = 16 * nt + r;
        const int pv = (p < 25) ? p : 0;
        const bf16x8 bv = *(const bf16x8*)(h4b_i + pv * 136 + ks * 32 + 8 * s);
        acc5[nt] = __builtin_amdgcn_mfma_f32_16x16x32_bf16(a5, bv, acc5[nt], 0, 0, 0);
      }
    }
    #pragma unroll
    for (int nt = 0; nt < 2; ++nt) {
      const int p = 16 * nt + r;
      if (p < 25) {
        #pragma unroll
        for (int rg = 0; rg < 4; ++rg) {
          const int fm = mt * 16 + 4 * s + rg;
          if (fm < 24) outs_s[img * 600 + fm * 25 + p] = acc5[nt][rg] + b5s[fm];
        }
      }
    }
  }
  bar_lds();

  // ================= att softmax (wave 0 -> img0, wave 2 -> img1) =================
  if (!(t & 64)) {
    const int im = t >> 7;
    const int tl = t & 63;
    float v = (tl < 25) ? outs_s[im * 600 + 575 + tl] : -1e30f;
    #pragma unroll
    for (int off = 32; off; off >>= 1) v = fmaxf(v, __shfl_xor(v, off));
    const float m = v;
    float e = (tl < 25) ? expf(outs_s[im * 600 + 575 + tl] - m) : 0.0f;
    float ss = e;
    #pragma unroll
    for (int off = 32; off; off >>= 1) ss += __shfl_xor(ss, off);
    if (tl < 25) att_s[im * 25 + tl] = e / ss;
  }
  bar_lds();

  // ================= pool =================
  {
    const int im = t >> 7;
    const int tl = t & 127;
    if (tl < 23) {
      float v = 0.f;
      #pragma unroll
      for (int p = 0; p < 25; ++p) v = fmaf(outs_s[im * 600 + tl * 25 + p], att_s[im * 25 + p], v);
      ps[im * 23 + tl] = v;
    }
  }
  bar_lds();

  // ================= pose + warp + softmax stats =================
  float dmv[2];
  #pragma unroll
  for (int im = 0; im < 2; ++im) {
    const int idx = (b0 + im) * KK + k;
    const float dl = ps[im * 23 + 6] + noise[idx];
    dmv[im] = 1.0f / (1.0f + expf(-dl));
  }

  #pragma unroll
  for (int im = 0; im < 2; ++im) {
    const int idx = (b0 + im) * KK + k;
    if (t < 144) {
      float v;
      if (t == 0)       v = dmv[im];
      else if (t < 7)   v = fmaxf(ps[im * 23 + t - 1], 0.0f);
      else if (t < 128) v = tm[t - 7];
      else              v = fmaxf(ps[im * 23 + 7 + (t - 128)], 0.0f);
      out[O_OCAE + (size_t)idx * 144 + t] = v;
    }
    if (t < 6) out[O_XM + (size_t)idx * 6 + t] = fmaxf(ps[im * 23 + t], 0.0f);
    if (t == 0) out[O_DM + idx] = dmv[im];
  }

  const int im = t >> 7;
  const int tl = t & 127;
  const int idx = (b0 + im) * KK + k;
  const float dm = dmv[im];

  const float D2R = 0.017453292519943295f;
  const float ang = fmaxf(ps[im * 23 + 0], 0.0f) * D2R;
  const float tx = fmaxf(ps[im * 23 + 1], 0.0f), ty = fmaxf(ps[im * 23 + 2], 0.0f);
  const float sc = fmaxf(ps[im * 23 + 3], 0.0f) + 1e-6f;
  const float sxr = fmaxf(ps[im * 23 + 4], 0.0f) * D2R;
  const float syr = fmaxf(ps[im * 23 + 5], 0.0f) * D2R;
  const float cas = cosf(ang - syr), sas = sinf(ang - syr);
  const float csy = cosf(syr), tsx = tanf(sxr);
  const float a_ = cas / csy;
  const float b_ = -cas * tsx / csy - sinf(ang);
  const float c_ = sas / csy;
  const float d_ = -sas * tsx / csy + cosf(ang);
  const float m00 = d_ / sc, m01 = -b_ / sc, m10 = -c_ / sc, m11 = a_ / sc;
  const float m02 = m00 * (-5.0f - tx) + m01 * (-5.0f - ty) + 5.0f;
  const float m12 = m10 * (-5.0f - tx) + m11 * (-5.0f - ty) + 5.0f;

  const float S = 0.275f;
  float ttv[13];
  float lmax = -1e30f;
  #pragma unroll
  for (int i = 0; i < 13; ++i) {
    const int pix = tl + 128 * i;
    float val2 = 0.0f;
    if (pix < 1600) {
      const int py = pix / 40, px = pix - 40 * py;
      const float u = (px + 0.5f) * S - 0.5f;
      const float v = (py + 0.5f) * S - 0.5f;
      const float sx = m00 * u + m01 * v + m02;
      const float sy = m10 * u + m11 * v + m12;
      const float x0 = floorf(sx), y0 = floorf(sy);
      const float wx = sx - x0, wy = sy - y0;
      const int xi = (int)x0, yi = (int)y0;
      const float v00 = tapf(tm, yi, xi);
      const float v01 = tapf(tm, yi, xi + 1);
      const float v10 = tapf(tm, yi + 1, xi);
      const float v11 = tapf(tm, yi + 1, xi + 1);
      const float val = (v00 * (1.0f - wx) + v01 * wx) * (1.0f - wy) + (v10 * (1.0f - wx) + v11 * wx) * wy;
      const ushort tb = f2bf(val);
      val2 = bf2f(tb);
      ttb[(size_t)idx * 1600 + pix] = tb;
      lmax = fmaxf(lmax, dm * val2);
    }
    ttv[i] = val2;
  }

  #pragma unroll
  for (int off = 32; off; off >>= 1) lmax = fmaxf(lmax, __shfl_xor(lmax, off));
  if ((t & 63) == 0) red[t >> 6] = lmax;
  bar_lds();
  const float m = fmaxf(red[2 * im], red[2 * im + 1]);
  float ls = 0.0f;
  #pragma unroll
  for (int i = 0; i < 13; ++i)
    if (tl + 128 * i < 1600) ls += expf(fmaf(dm, ttv[i], -m));
  #pragma unroll
  for (int off = 32; off; off >>= 1) ls += __shfl_xor(ls, off);
  bar_lds();
  if ((t & 63) == 0) red[4 + (t >> 6)] = ls;
  bar_lds();
  if ((t & 127) == 0) {
    smax[idx] = m;
    sden[idx] = red[4 + 2 * im] + red[5 + 2 * im];
    dmw[idx] = dm;
  }
}

// ---------------- per-pixel mixture + log ----------------
__global__ __launch_bounds__(256) void k_ll(
    const float* __restrict__ x, const ushort* __restrict__ ttb,
    const float* __restrict__ smax, const float* __restrict__ sden,
    const float* __restrict__ dmw, float* __restrict__ part)
{
  const int b = blockIdx.x >> 2;
  const int chunk = blockIdx.x & 3;
  const int t = threadIdx.x;

  __shared__ __align__(16) float xs[1600];
  __shared__ float kd[24], km[24], ki[24];
  __shared__ float red[4], red2[4];

  for (int i = t; i < 400; i += 256)
    ((float4*)xs)[i] = ((const float4*)(x + (size_t)b * 1600))[i];
  if (t < 24) {
    kd[t] = dmw[b * 24 + t];
    km[t] = smax[b * 24 + t];
    ki[t] = 1.0f / sden[b * 24 + t];
  }
  __syncthreads();

  float s1 = 0.f, s2 = 0.f;
  for (int i = t; i < 1600; i += 256) { const float v = xs[i]; s1 += v; s2 = fmaf(v, v, s2); }
  #pragma unroll
  for (int off = 32; off; off >>= 1) { s1 += __shfl_xor(s1, off); s2 += __shfl_xor(s2, off); }
  if ((t & 63) == 0) { red[t >> 6] = s1; red2[t >> 6] = s2; }
  __syncthreads();
  s1 = red[0] + red[1] + red[2] + red[3];
  s2 = red2[0] + red2[1] + red2[2] + red2[3];
  const float var = (s2 - s1 * s1 * (1.0f / 1600.0f)) * (1.0f / 1599.0f);
  const float stdv = sqrtf(var);
  const float mult = 1.0f / sqrtf(stdv * 6.283185307179586f);
  const float pmul = -1.0f / (2.0f * stdv * stdv);

  const int p0 = chunk * 400;
  float ll = 0.0f;
  for (int ii = t; ii < 400; ii += 256) {
    const int pix = p0 + ii;
    const float xv = xs[pix];
    float sum = 0.0f;
    #pragma unroll 6
    for (int kk2 = 0; kk2 < 24; ++kk2) {
      const float tv = bf2f(ttb[(size_t)(b * 24 + kk2) * 1600 + pix]);
      const float dxv = xv - tv;
      sum += expf(fmaf(dxv * dxv, pmul, fmaf(kd[kk2], tv, -km[kk2]))) * ki[kk2];
    }
    ll += logf(mult * sum);
  }
  #pragma unroll
  for (int off = 32; off; off >>= 1) ll += __shfl_xor(ll, off);
  __syncthreads();
  if ((t & 63) == 0) red[t >> 6] = ll;
  __syncthreads();
  if (t == 0) part[blockIdx.x] = red[0] + red[1] + red[2] + red[3];
}

__global__ void k_final(const float* __restrict__ part, float* __restrict__ out)
{
  const int t = threadIdx.x;
  float v = part[t] + part[t + 256];
  #pragma unroll
  for (int off = 32; off; off >>= 1) v += __shfl_xor(v, off);
  __shared__ float red[4];
  if ((t & 63) == 0) red[t >> 6] = v;
  __syncthreads();
  if (t == 0) out[0] = (red[0] + red[1] + red[2] + red[3]) * (1.0f / 128.0f);
}

extern "C" void kernel_launch(void* const* d_in, const int* in_sizes, int n_in,
                              void* d_out, int out_size, void* d_ws, size_t ws_size,
                              hipStream_t stream)
{
  const float* x     = (const float*)d_in[0];
  const float* noise = (const float*)d_in[1];
  const float* W1    = (const float*)d_in[2];
  const float* b1    = (const float*)d_in[3];
  const float* W2    = (const float*)d_in[4];
  const float* b2    = (const float*)d_in[5];
  const float* W3    = (const float*)d_in[6];
  const float* b3    = (const float*)d_in[7];
  const float* W4    = (const float*)d_in[8];
  const float* b4    = (const float*)d_in[9];
  const float* W5    = (const float*)d_in[10];
  const float* b5    = (const float*)d_in[11];
  const float* tmpl  = (const float*)d_in[12];
  float* out = (float*)d_out;
  char* wsb = (char*)d_ws;

  ushort* W1p = (ushort*)(wsb + OFF_W1P);
  ushort* W5p = (ushort*)(wsb + OFF_W5P);
  ushort* W2p = (ushort*)(wsb + OFF_WB2);
  ushort* W3p = (ushort*)(wsb + OFF_WB3);
  ushort* W4p = (ushort*)(wsb + OFF_WB4);
  ushort* ttp  = (ushort*)(wsb + OFF_TT);
  float* smaxp = (float*)(wsb + OFF_SMAX);
  float* sdenp = (float*)(wsb + OFF_SDEN);
  float* dmp   = (float*)(wsb + OFF_DM);
  float* partp = (float*)(wsb + OFF_PART);

  k_w1p<<<24, 128, 0, stream>>>(W1, W5, b1, W1p, W5p);
  k_wp<<<1152, 256, 0, stream>>>(W2, W3, W4, W2p, W3p, W4p);
  k_tower<<<KK * BB / 2, 256, 0, stream>>>(x, W1p, W2p, b2, W3p, b3, W4p, b4,
                                           W5p, b5, noise, tmpl, out, ttp, smaxp, sdenp, dmp);
  k_ll<<<BB * 4, 256, 0, stream>>>(x, ttp, smaxp, sdenp, dmp, partp);
  k_final<<<1, 256, 0, stream>>>(partp, out);
}